// Round 15
// baseline (1594.997 us; speedup 1.0000x reference)
//
#include <hip/hip_runtime.h>
#include <math.h>

#define NPROTO 8
#define KV_NCH 4
#define MSG_NCH 8

typedef __attribute__((ext_vector_type(8))) short short8;
typedef __attribute__((ext_vector_type(4))) float floatx4;

static __device__ __forceinline__ ushort f2b(float f) {
    unsigned u = __builtin_bit_cast(unsigned, f);
    unsigned r = (u + 0x7fffu + ((u >> 16) & 1u)) >> 16;
    return (ushort)r;
}

static __device__ __forceinline__ float b2f(ushort u) {
    return __builtin_bit_cast(float, ((unsigned)u) << 16);
}

typedef __attribute__((address_space(1))) void gvoid;
typedef __attribute__((address_space(3))) void lvoid;

// async global->LDS, 16B per lane. LDS dest must be lane-contiguous per wave.
static __device__ __forceinline__ void gload_lds16(const ushort* g, ushort* l) {
    __builtin_amdgcn_global_load_lds((gvoid*)(void*)g, (lvoid*)l, 16, 0, 0);
}

// ---------------- prototype projection / argmax-class kernel ----------------
__global__ __launch_bounds__(256) void lft_class_kernel(
    const float* __restrict__ f0wo, const float* __restrict__ f1wo,
    const int* __restrict__ mask0, const int* __restrict__ mask1,
    const float* __restrict__ proto,
    float* out, int* cls0, int* cls1)
{
    __shared__ float pr[2048];
    int t = threadIdx.x;
    *(float4*)&pr[t * 4]        = *(const float4*)&proto[t * 4];
    *(float4*)&pr[1024 + t * 4] = *(const float4*)&proto[1024 + t * 4];
    __syncthreads();
    int wave = t >> 6, lane = t & 63;
    long token = (long)blockIdx.x * 4 + wave;
    const float* fsrc; const int* msrc; float* fpout; float* clsout; int* clsarr; long tok;
    if (token < 38400) {
        tok = token; fsrc = f0wo; msrc = mask0;
        fpout = out + 19737600L; clsout = out + 19660800L; clsarr = cls0;
    } else {
        tok = token - 38400; fsrc = f1wo; msrc = mask1;
        fpout = out + 20044800L; clsout = out + 19699200L; clsarr = cls1;
    }
    float4 f = *(const float4*)&fsrc[tok * 256 + lane * 4];
    float s[NPROTO];
#pragma unroll
    for (int p = 0; p < NPROTO; p++) {
        float4 pv = *(const float4*)&pr[p * 256 + lane * 4];
        s[p] = f.x * pv.x + f.y * pv.y + f.z * pv.z + f.w * pv.w;
    }
    float k0_ = (lane & 1) ? s[4] : s[0], d0 = (lane & 1) ? s[0] : s[4];
    float k1_ = (lane & 1) ? s[5] : s[1], d1 = (lane & 1) ? s[1] : s[5];
    float k2_ = (lane & 1) ? s[6] : s[2], d2 = (lane & 1) ? s[2] : s[6];
    float k3_ = (lane & 1) ? s[7] : s[3], d3 = (lane & 1) ? s[3] : s[7];
    float w0 = k0_ + __shfl_xor(d0, 1, 64);
    float w1 = k1_ + __shfl_xor(d1, 1, 64);
    float w2 = k2_ + __shfl_xor(d2, 1, 64);
    float w3 = k3_ + __shfl_xor(d3, 1, 64);
    float u0k = (lane & 2) ? w2 : w0, u0d = (lane & 2) ? w0 : w2;
    float u1k = (lane & 2) ? w3 : w1, u1d = (lane & 2) ? w1 : w3;
    float x0 = u0k + __shfl_xor(u0d, 2, 64);
    float x1 = u1k + __shfl_xor(u1d, 2, 64);
    float yk = (lane & 4) ? x1 : x0, yd = (lane & 4) ? x0 : x1;
    float sc = yk + __shfl_xor(yd, 4, 64);
    sc += __shfl_xor(sc, 8, 64);
    sc += __shfl_xor(sc, 16, 64);
    sc += __shfl_xor(sc, 32, 64);
    int p = ((lane & 1) << 2) | (lane & 2) | ((lane >> 2) & 1);
    if (lane < 8) fpout[tok * 8 + p] = sc;
    float bv = sc; int bi = p;
#pragma unroll
    for (int o = 1; o < 8; o <<= 1) {
        float ov = __shfl_xor(bv, o, 64);
        int oi = __shfl_xor(bi, o, 64);
        if (ov > bv || (ov == bv && oi < bi)) { bv = ov; bi = oi; }
    }
    if (lane == 0) {
        clsout[tok] = (float)bi;
        clsarr[tok] = msrc[tok] ? bi : -1;
    }
}

// ---------------- counting sort of tokens by (batch,class) -------------------
__global__ __launch_bounds__(256) void lft_sort_kernel(
    const int* __restrict__ cls0, const int* __restrict__ cls1,
    int* tl0, int* tl1, int* meta)
{
    int g = blockIdx.x; int L = g >> 3, b = g & 7;
    const int* cls = (L ? cls1 : cls0) + b * 4800;
    int* tl = (L ? tl1 : tl0) + b * 4800;
    int* mt = meta + (L * 8 + b) * 16;
    __shared__ int cnt[8], base[8], pos[8];
    int t = threadIdx.x;
    if (t < 8) cnt[t] = 0;
    __syncthreads();
    for (int tok = t; tok < 4800; tok += 256) {
        int c = cls[tok];
        if (c >= 0) atomicAdd(&cnt[c], 1);
    }
    __syncthreads();
    if (t == 0) {
        int s = 0;
        for (int c = 0; c < 8; c++) { base[c] = s; pos[c] = s; s += cnt[c]; }
    }
    __syncthreads();
    if (t < 8) { mt[t * 2] = base[t]; mt[t * 2 + 1] = cnt[t]; }
    for (int tok = t; tok < 4800; tok += 256) {
        int c = cls[tok];
        if (c >= 0) { int p = atomicAdd(&pos[c], 1); tl[p] = tok; }
    }
}

// ---------------- weight convert + transpose: Wt[n*K+k] = bf16(W[k*N+n]) ----
__global__ __launch_bounds__(256) void lft_wconv_kernel(
    const float* W0, const float* W1p, const float* W2p, const float* W3p,
    int K, int N, int nTypes, ushort* dst)
{
    int z = blockIdx.z;
    int li = z / nTypes, mi = z % nTypes;
    const float* srcs[4] = {W0, W1p, W2p, W3p};
    const float* src = srcs[mi] + (size_t)li * K * N;
    ushort* outp = dst + (size_t)z * K * N;
    __shared__ float tile[32][33];
    int k0 = blockIdx.x * 32, n0 = blockIdx.y * 32;
    int t = threadIdx.x;
    int r = t >> 3, c4 = (t & 7) << 2;
    float4 v = *(const float4*)&src[(size_t)(k0 + r) * N + n0 + c4];
    tile[r][c4] = v.x; tile[r][c4 + 1] = v.y; tile[r][c4 + 2] = v.z; tile[r][c4 + 3] = v.w;
    __syncthreads();
    ushort4 o;
    o.x = f2b(tile[c4 + 0][r]);
    o.y = f2b(tile[c4 + 1][r]);
    o.z = f2b(tile[c4 + 2][r]);
    o.w = f2b(tile[c4 + 3][r]);
    *(ushort4*)&outp[(size_t)(n0 + r) * K + k0 + c4] = o;
}

// ---------------- bf16 cast of feat0/feat1 (shadows only) ----------------
__global__ __launch_bounds__(256) void lft_cast_kernel(
    const float* __restrict__ f0, const float* __restrict__ f1,
    ushort* fab, ushort* fbb)
{
    long idx = ((long)blockIdx.x * 256 + threadIdx.x) * 4;
    const float* src; ushort* db; long o;
    if (idx < 9830400L) { src = f0; db = fab; o = idx; }
    else                { src = f1; db = fbb; o = idx - 9830400L; }
    float4 v = *(const float4*)&src[o];
    ushort4 u; u.x = f2b(v.x); u.y = f2b(v.y); u.z = f2b(v.z); u.w = f2b(v.w);
    *(ushort4*)&db[o] = u;
}

// ---------------- bf16 MFMA GEMM, 2-phase pipelined: C = act([A0|A1] @ Wt^T) -
// 128x128 tile, BK=32, dbuf LDS, gload_lds dwordx4, counted vmcnt(4).
// Source-col swizzle (rule #21), XCD remap (T1), transposed-operand vectorized
// epilogue. Split output by n0 (Cb2/colSplit).
__global__ __launch_bounds__(256) void lft_mfma_gemm(
    const ushort* __restrict__ A0, const ushort* __restrict__ A1, int kSplit,
    const ushort* __restrict__ Wt,
    float* Cf, ushort* Cb, int N, int K, int act, int actSplit,
    ushort* Cb2, int N2, int colSplit)
{
    __shared__ ushort As[2][128 * 32];
    __shared__ ushort Bs[2][128 * 32];
    int t = threadIdx.x;
    int nbx = gridDim.x;
    int nwg = nbx * gridDim.y;
    int orig = blockIdx.y * nbx + blockIdx.x;
    int q8 = nwg >> 3;
    int swz = (nwg & 7) ? orig : ((orig & 7) * q8 + (orig >> 3));
    int bx = swz % nbx, by = swz / nbx;
    int m0 = by << 7;
    int n0 = bx << 7;
    int wave = t >> 6, lane = t & 63;
    int wm = wave >> 1, wn = wave & 1;
    int l16 = lane & 15, quad = lane >> 4;
    int r = t >> 2;
    int cu = (t & 3) << 3;
    int fso = (((t & 3) ^ ((r ^ (r >> 2)) & 3)) << 3);
    floatx4 acc[4][4] = {};

    auto stage = [&](int buf, int k0) {
        const ushort* Asrc; int kcol, ldA;
        if (k0 < kSplit) { Asrc = A0; kcol = k0;          ldA = kSplit; }
        else             { Asrc = A1; kcol = k0 - kSplit; ldA = K - kSplit; }
        gload_lds16(&Asrc[(size_t)(m0 + r) * ldA + kcol + fso],      &As[buf][r * 32 + cu]);
        gload_lds16(&Asrc[(size_t)(m0 + r + 64) * ldA + kcol + fso], &As[buf][(r + 64) * 32 + cu]);
        gload_lds16(&Wt[(size_t)(n0 + r) * K + k0 + fso],            &Bs[buf][r * 32 + cu]);
        gload_lds16(&Wt[(size_t)(n0 + r + 64) * K + k0 + fso],       &Bs[buf][(r + 64) * 32 + cu]);
    };

    int qs = ((quad ^ ((l16 ^ (l16 >> 2)) & 3)) << 3);
    stage(0, 0);
    int cur = 0;
    for (int k0 = 0; k0 < K; k0 += 32) {
        if (k0 + 32 < K) {
            stage(cur ^ 1, k0 + 32);
            asm volatile("s_waitcnt vmcnt(4)" ::: "memory");
        } else {
            asm volatile("s_waitcnt vmcnt(0)" ::: "memory");
        }
        __builtin_amdgcn_s_barrier();
        short8 af[4], bfr[4];
#pragma unroll
        for (int i = 0; i < 4; i++) {
            af[i]  = *(const short8*)&As[cur][(wm * 64 + i * 16 + l16) * 32 + qs];
            bfr[i] = *(const short8*)&Bs[cur][(wn * 64 + i * 16 + l16) * 32 + qs];
        }
#pragma unroll
        for (int i = 0; i < 4; i++)
#pragma unroll
            for (int j = 0; j < 4; j++)
                acc[i][j] = __builtin_amdgcn_mfma_f32_16x16x32_bf16(bfr[j], af[i], acc[i][j], 0, 0, 0);
        asm volatile("" ::: "memory");
        __builtin_amdgcn_s_barrier();
        cur ^= 1;
    }
    int effAct = (n0 >= actSplit) ? 0 : act;
    float* Cfp = Cf;
    ushort* Cbp = Cb;
    int ldC = N, cb0 = n0;
    if (Cb2 && n0 >= colSplit) { Cbp = Cb2; Cfp = nullptr; ldC = N2; cb0 = n0 - colSplit; }
#pragma unroll
    for (int i = 0; i < 4; i++) {
        long rowb = m0 + wm * 64 + i * 16 + l16;
#pragma unroll
        for (int j = 0; j < 4; j++) {
            int colb = cb0 + wn * 64 + j * 16 + quad * 4;
            float v0 = acc[i][j][0], v1 = acc[i][j][1], v2 = acc[i][j][2], v3 = acc[i][j][3];
            if (effAct == 1) {
                v0 = v0 > 0.f ? v0 + 1.f : __expf(v0);
                v1 = v1 > 0.f ? v1 + 1.f : __expf(v1);
                v2 = v2 > 0.f ? v2 + 1.f : __expf(v2);
                v3 = v3 > 0.f ? v3 + 1.f : __expf(v3);
            } else if (effAct == 2) {
                v0 = fmaxf(v0, 0.f); v1 = fmaxf(v1, 0.f);
                v2 = fmaxf(v2, 0.f); v3 = fmaxf(v3, 0.f);
            }
            if (Cfp) {
                float4 f4; f4.x = v0; f4.y = v1; f4.z = v2; f4.w = v3;
                *(float4*)&Cfp[rowb * ldC + colb] = f4;
            }
            if (Cbp) {
                ushort4 u4;
                u4.x = f2b(v0); u4.y = f2b(v1); u4.z = f2b(v2); u4.w = f2b(v3);
                *(ushort4*)&Cbp[rowb * ldC + colb] = u4;
            }
        }
    }
}

// ---------------- fused GEMM (N=256 full-row) + LayerNorm epilogue -----------
// 64x256 tile, 4 waves (1x4 col-quarters, 64x64 each), 600 blocks.
// HYBRID BK: A (HBM stream) staged at BK=64 granularity -> each staging
// instruction covers FULL 128B rows (8 rows x 128B) halving HBM request
// count vs 64B segments. B (L2-resident weights) stays BK=32 dbuf.
// A-swizzle: LDS unit u of row holds global unit u^(row&7); read applies the
// same XOR -> even 8-lanes-per-bank-group, conflict-free.
// vmcnt: 6 on A-staging steps (A 2 + B 4 newer), 4 otherwise, 0 last.
__global__ __launch_bounds__(256) void lft_gemm_ln(
    const ushort* __restrict__ A, const ushort* __restrict__ Wt, int K,
    const float* __restrict__ g, const float* __restrict__ bb,
    const float* __restrict__ resid, const int* __restrict__ cls,
    float* outF, ushort* __restrict__ outB)
{
    __shared__ ushort As[2][64 * 64];   // A: BK=64 tiles, 8KB each
    __shared__ ushort Bs[2][256 * 32];  // B: BK=32 tiles, 16KB each
    __shared__ float red[4][64][2];
    int t = threadIdx.x;                  // 0..255
    long m0 = (long)blockIdx.x << 6;
    int wave = t >> 6, lane = t & 63;
    int wn = wave;                        // 1 x 4 wave grid (col quarters)
    int l16 = lane & 15, quad = lane >> 4;
    int r = t >> 2;                       // 0..63 (B staging row)
    int cu = (t & 3) << 3;
    int fso = (((t & 3) ^ ((r ^ (r >> 2)) & 3)) << 3);  // B source swizzle
    floatx4 acc[4][4] = {};

    // A: 64 rows x 64 ushorts = 512 16B-units; 2 instructions/thread.
    // Instruction qq covers units u = qq*256 + t (lane-linear LDS dest).
    auto stageA = [&](int buf, int k0) {
#pragma unroll
        for (int qq = 0; qq < 2; qq++) {
            int u = qq * 256 + t;
            int row = u >> 3, c8 = u & 7;
            gload_lds16(&A[(m0 + row) * K + k0 + ((c8 ^ (row & 7)) << 3)],
                        &As[buf][row * 64 + (c8 << 3)]);
        }
    };
    auto stageB = [&](int buf, int k0) {
#pragma unroll
        for (int s = 0; s < 4; s++)
            gload_lds16(&Wt[(size_t)(s * 64 + r) * K + k0 + fso],
                        &Bs[buf][(s * 64 + r) * 32 + cu]);
    };

    int qs = ((quad ^ ((l16 ^ (l16 >> 2)) & 3)) << 3);  // B read swizzle
    int nk = K >> 5;        // number of 32-wide compute steps
    int na = nk >> 1;       // number of 64-wide A tiles
    stageA(0, 0);
    stageB(0, 0);
    for (int k = 0; k < nk; k++) {
        int p = k & 1;          // parity within current A64 tile
        int ao = k >> 1;        // current A tile index
        bool stA = (p == 0) && (ao + 1 < na);
        if (stA) stageA((ao + 1) & 1, (ao + 1) << 6);
        if (k + 1 < nk) {
            stageB((k + 1) & 1, (k + 1) << 5);
            if (stA) { asm volatile("s_waitcnt vmcnt(6)" ::: "memory"); }
            else     { asm volatile("s_waitcnt vmcnt(4)" ::: "memory"); }
        } else {
            asm volatile("s_waitcnt vmcnt(0)" ::: "memory");
        }
        __builtin_amdgcn_s_barrier();
        const ushort* Ac = As[ao & 1];
        short8 af[4], bfr[4];
#pragma unroll
        for (int i = 0; i < 4; i++) {
            int row = i * 16 + l16;
            af[i]  = *(const short8*)&Ac[row * 64 + ((((p << 2) + quad) ^ (row & 7)) << 3)];
            bfr[i] = *(const short8*)&Bs[k & 1][(wn * 64 + i * 16 + l16) * 32 + qs];
        }
        // transposed-operand: lane l16 = row (m-local), quad*4+rr = 4 consec cols
#pragma unroll
        for (int i = 0; i < 4; i++)
#pragma unroll
            for (int j = 0; j < 4; j++)
                acc[i][j] = __builtin_amdgcn_mfma_f32_16x16x32_bf16(bfr[j], af[i], acc[i][j], 0, 0, 0);
        asm volatile("" ::: "memory");
        __builtin_amdgcn_s_barrier();
    }
    // ---- row sums: lane covers 16 cols of each of its 4 row-frags; reduce
    // over quad (shfl), then combine the 4 col-quarter waves via LDS ----
#pragma unroll
    for (int i = 0; i < 4; i++) {
        float s = 0.f, sq = 0.f;
#pragma unroll
        for (int j = 0; j < 4; j++)
#pragma unroll
            for (int rr = 0; rr < 4; rr++) { float v = acc[i][j][rr]; s += v; sq += v * v; }
        s  += __shfl_xor(s, 16, 64);  sq += __shfl_xor(sq, 16, 64);
        s  += __shfl_xor(s, 32, 64);  sq += __shfl_xor(sq, 32, 64);
        if (quad == 0) {
            int rl = i * 16 + l16;
            red[wn][rl][0] = s;
            red[wn][rl][1] = sq;
        }
    }
    __syncthreads();
#pragma unroll
    for (int i = 0; i < 4; i++) {
        int rl = i * 16 + l16;
        long row = m0 + rl;
        float tsum = red[0][rl][0] + red[1][rl][0] + red[2][rl][0] + red[3][rl][0];
        float tsq  = red[0][rl][1] + red[1][rl][1] + red[2][rl][1] + red[3][rl][1];
        float mean = tsum * (1.0f / 256.0f);
        float var  = tsq * (1.0f / 256.0f) - mean * mean;
        float rsq  = rsqrtf(var + 1e-5f);
        bool keep = true;
        if (cls) keep = (cls[row] >= 0);
#pragma unroll
        for (int j = 0; j < 4; j++) {
            int col = wn * 64 + j * 16 + quad * 4;
            float4 gv = *(const float4*)&g[col];
            float4 bv = *(const float4*)&bb[col];
            float y0 = (acc[i][j][0] - mean) * rsq * gv.x + bv.x;
            float y1 = (acc[i][j][1] - mean) * rsq * gv.y + bv.y;
            float y2 = (acc[i][j][2] - mean) * rsq * gv.z + bv.z;
            float y3 = (acc[i][j][3] - mean) * rsq * gv.w + bv.w;
            if (resid) {
                float4 xr = *(const float4*)&resid[row * 256 + col];
                if (keep) { y0 += xr.x; y1 += xr.y; y2 += xr.z; y3 += xr.w; }
                else      { y0 = xr.x;  y1 = xr.y;  y2 = xr.z;  y3 = xr.w; }
            }
            if (outF) {
                float4 f4; f4.x = y0; f4.y = y1; f4.z = y2; f4.w = y3;
                *(float4*)&outF[row * 256 + col] = f4;
            }
            ushort4 u4;
            u4.x = f2b(y0); u4.y = f2b(y1); u4.z = f2b(y2); u4.w = f2b(y3);
            *(ushort4*)&outB[row * 256 + col] = u4;
        }
    }
}

// ---------------- per-class KV / Ksum reduction (SRC-side token lists) --------
__global__ __launch_bounds__(256) void lft_kv_kernel(
    const ushort* __restrict__ kvab,
    const int* __restrict__ tlist, const int* __restrict__ meta,
    float* kv, float* ksum)
{
    int chunk = blockIdx.x, c = blockIdx.y;
    int b = blockIdx.z >> 3, h = blockIdx.z & 7;
    int off = meta[(b * 8 + c) * 2], n = meta[(b * 8 + c) * 2 + 1];
    int per = (n + KV_NCH - 1) / KV_NCH;
    int s0 = chunk * per;
    int s1 = min(s0 + per, n);
    if (s0 >= s1) return;
    const int* tl = tlist + b * 4800 + off;
    int t = threadIdx.x;
    __shared__ float kb[8][32];
    __shared__ float vb[8][32];
    int od = t >> 3, oe = (t & 7) << 2;
    int lt = t >> 5, ld = t & 31;
    float a0 = 0.f, a1 = 0.f, a2 = 0.f, a3 = 0.f, ak = 0.f;
    for (int s = s0; s < s1; s += 8) {
        float kval = 0.f, vval = 0.f;
        if (s + lt < s1) {
            int tok = tl[s + lt];
            long bse = ((long)b * 4800 + tok) * 512 + h * 32 + ld;
            kval = b2f(kvab[bse]);
            vval = b2f(kvab[bse + 256]);
        }
        __syncthreads();
        kb[lt][ld] = kval;
        vb[lt][ld] = vval;
        __syncthreads();
#pragma unroll
        for (int j = 0; j < 8; j++) {
            float kd = kb[j][od];
            float4 vv = *(const float4*)&vb[j][oe];
            a0 += kd * vv.x; a1 += kd * vv.y; a2 += kd * vv.z; a3 += kd * vv.w;
            ak += kd;
        }
    }
    float* dst = kv + (((long)(b * NPROTO + c) * 8 + h) << 10) + od * 32 + oe;
    atomicAdd(dst + 0, a0);
    atomicAdd(dst + 1, a1);
    atomicAdd(dst + 2, a2);
    atomicAdd(dst + 3, a3);
    if ((t & 7) == 0)
        atomicAdd(ksum + (((long)(b * NPROTO + c) * 8 + h) << 5) + od, ak);
}

// ---------------- kv fp32 [d][e] + ksum → bf16 B-layout [e'][d], e'<48 -------
__global__ __launch_bounds__(256) void lft_kvconv_kernel(
    const float* __restrict__ kvb, const float* __restrict__ ksb,
    ushort* __restrict__ kvt)
{
    int bc = blockIdx.x;          // b*8+c
    int t = threadIdx.x;
    int h = t >> 5, d = t & 31;
    const float* kvsrc = kvb + ((long)bc * 8 + h) * 1024;
    const float* kssrc = ksb + ((long)bc * 8 + h) * 32;
    ushort* dst = kvt + ((long)bc * 8 + h) * 1536;
#pragma unroll
    for (int e = 0; e < 32; e++) dst[e * 32 + d] = f2b(kvsrc[d * 32 + e]);
    dst[32 * 32 + d] = f2b(kssrc[d]);
#pragma unroll
    for (int e = 33; e < 48; e++) dst[e * 32 + d] = 0;
}

// ---------------- msg via MFMA over X-SIDE class-sorted lists ----------------
__global__ __launch_bounds__(256) void lft_msg_kernel(
    const ushort* __restrict__ pq, const ushort* __restrict__ kvt,
    const int* __restrict__ tlist, const int* __restrict__ meta,
    ushort* __restrict__ msg)
{
    int chunk = blockIdx.x, c = blockIdx.y, b = blockIdx.z;
    int off = meta[(b * 8 + c) * 2], n = meta[(b * 8 + c) * 2 + 1];
    int per = (n + MSG_NCH - 1) / MSG_NCH;
    int s0 = chunk * per, s1 = min(s0 + per, n);
    if (s0 >= s1) return;
    const int* tl = tlist + b * 4800 + off;
    int t = threadIdx.x;
    int wave = t >> 6, lane = t & 63;
    int l16 = lane & 15, quad = lane >> 4;
    int bc = b * 8 + c;
    short8 bfr[2][3];
#pragma unroll
    for (int hh = 0; hh < 2; hh++) {
        int h = wave * 2 + hh;
        const ushort* kb = kvt + ((long)bc * 8 + h) * 1536;
#pragma unroll
        for (int nt = 0; nt < 3; nt++)
            bfr[hh][nt] = *(const short8*)&kb[(nt * 16 + l16) * 32 + quad * 8];
    }
    for (int s = s0; s < s1; s += 16) {
        int ia = min(s + l16, s1 - 1);
        int tokA = tl[ia];
        long rowA = (long)b * 4800 + tokA;
#pragma unroll
        for (int hh = 0; hh < 2; hh++) {
            int h = wave * 2 + hh;
            short8 a = *(const short8*)&pq[rowA * 256 + h * 32 + quad * 8];
            floatx4 n0 = {}, n1 = {}, dd = {};
            n0 = __builtin_amdgcn_mfma_f32_16x16x32_bf16(a, bfr[hh][0], n0, 0, 0, 0);
            n1 = __builtin_amdgcn_mfma_f32_16x16x32_bf16(a, bfr[hh][1], n1, 0, 0, 0);
            dd = __builtin_amdgcn_mfma_f32_16x16x32_bf16(a, bfr[hh][2], dd, 0, 0, 0);
#pragma unroll
            for (int r = 0; r < 4; r++) {
                int rowi = s + quad * 4 + r;
                float den = __shfl(dd[r], lane & 48, 64);
                float inv = 1.f / (den + 1e-6f);
                int tokr = __shfl(tokA, quad * 4 + r, 64);
                if (rowi < s1) {
                    long base = ((long)b * 4800 + tokr) * 256 + h * 32;
                    msg[base + l16]      = f2b(n0[r] * inv);
                    msg[base + 16 + l16] = f2b(n1[r] * inv);
                }
            }
        }
    }
}

extern "C" void kernel_launch(void* const* d_in, const int* in_sizes, int n_in,
                              void* d_out, int out_size, void* d_ws, size_t ws_size,
                              hipStream_t stream)
{
    (void)in_sizes; (void)n_in; (void)out_size; (void)ws_size;
    const float* feat0 = (const float*)d_in[0];
    const float* feat1 = (const float*)d_in[1];
    const int*   mask0 = (const int*)d_in[2];
    const int*   mask1 = (const int*)d_in[3];
    const float* f0wo  = (const float*)d_in[4];
    const float* f1wo  = (const float*)d_in[5];
    const float* proto = (const float*)d_in[6];
    const float* Wq = (const float*)d_in[7];
    const float* Wk = (const float*)d_in[8];
    const float* Wv = (const float*)d_in[9];
    const float* Wm = (const float*)d_in[10];
    const float* W1 = (const float*)d_in[11];
    const float* W2 = (const float*)d_in[12];
    const float* g1 = (const float*)d_in[13];
    const float* b1 = (const float*)d_in[14];
    const float* g2 = (const float*)d_in[15];
    const float* b2 = (const float*)d_in[16];
    float* out = (float*)d_out;
    float* ws = (float*)d_ws;

    // ---- workspace layout ----
    const long FSZ = 9830400L;           // 8*4800*256
    float* fa   = ws;                    // fp32 master feat0
    float* fb   = ws + FSZ;              // fp32 master feat1
    float* vbuf = ws + 3 * FSZ;          // bf16 [38400][512]: kv fused out, later hid
    ushort* ub  = (ushort*)(ws + 4 * FSZ);
    ushort* fa_bf  = ub;                 // bf16 shadow of fa
    ushort* fb_bf  = ub + FSZ;           // bf16 shadow of fb
    ushort* msg_bf = ub + 2 * FSZ;       // msg bf16; later LN1 bf16 out (in-place)
    ushort* qb_bf  = ub + 3 * FSZ;       // phi_q bf16
    ushort* wb     = ub + 4 * FSZ;       // bf16 transposed weights
    ushort* wb1    = wb + 16 * 65536;    // W1^T per layer [512][512]
    ushort* wb2    = wb1 + 4 * 262144;   // W2^T per layer [256][512]
    ushort* kvt    = wb2 + 4 * 131072;   // [64][8][48][32] bf16
    float* kvb = (float*)(kvt + 786432); // [B,NP,H,D,D] = 524288 f
    float* ksb = kvb + 524288;           // [B,NP,H,D]   = 16384 f
    int* cls0 = (int*)(ksb + 16384);
    int* cls1 = cls0 + 38400;
    int* tl0  = cls1 + 38400;            // class-sorted token lists
    int* tl1  = tl0 + 38400;
    int* meta = tl1 + 38400;             // [2][8][8][2] (off,cnt)
    ushort* kvab   = (ushort*)vbuf;      // [38400,512] bf16: [phi_k | v]
    ushort* hid_bf = (ushort*)vbuf;      // [38400,512] bf16 (after kv consumed)

    // one-time per launch
    lft_wconv_kernel<<<dim3(8, 8, 16), 256, 0, stream>>>(Wq, Wk, Wv, Wm, 256, 256, 4, wb);
    lft_wconv_kernel<<<dim3(16, 16, 4), 256, 0, stream>>>(W1, W1, W1, W1, 512, 512, 1, wb1);
    lft_wconv_kernel<<<dim3(16, 8, 4), 256, 0, stream>>>(W2, W2, W2, W2, 512, 256, 1, wb2);
    lft_cast_kernel<<<19200, 256, 0, stream>>>(feat0, feat1, fa_bf, fb_bf);
    hipMemcpyAsync(out + 20352000L, proto, 2048 * 4, hipMemcpyDeviceToDevice, stream);
    lft_class_kernel<<<19200, 256, 0, stream>>>(f0wo, f1wo, mask0, mask1, proto,
                                                out, cls0, cls1);
    lft_sort_kernel<<<16, 256, 0, stream>>>(cls0, cls1, tl0, tl1, meta);

    for (int li = 0; li < 4; li++) {
        const ushort* wq = wb + (size_t)(li * 4 + 0) * 65536;  // wq|wk|wv contig: [768][256]
        const ushort* wk = wb + (size_t)(li * 4 + 1) * 65536;  // wk|wv contiguous: [512][256]
        const ushort* wm = wb + (size_t)(li * 4 + 3) * 65536;
        const ushort* w1 = wb1 + (size_t)li * 262144;
        const ushort* w2 = wb2 + (size_t)li * 131072;
        const float* g1p = g1 + li * 256; const float* b1p = b1 + li * 256;
        const float* g2p = g2 + li * 256; const float* b2p = b2 + li * 256;

        auto call = [&](ushort* x_bf, ushort* s_bf, const int* clsx,
                        const int* tlx, const int* mtx,
                        const int* tls, const int* mts,
                        const float* residp, float* outFp) {
            dim3 blk(256);
            dim3 gA(2, 300), gB(4, 300), gQ(6, 300);
            if (x_bf == s_bf) {
                // self-self: fused [q|phi_k|v] = x@[Wq|Wk|Wv], N=768, split out
                lft_mfma_gemm<<<gQ, blk, 0, stream>>>(x_bf, x_bf, 256, wq,
                    nullptr, qb_bf, 256, 256, 1, 512, kvab, 512, 256);
            } else {
                lft_mfma_gemm<<<gA, blk, 0, stream>>>(x_bf, x_bf, 256, wq,
                    nullptr, qb_bf, 256, 256, 1, 256, nullptr, 0, 0);
                lft_mfma_gemm<<<gB, blk, 0, stream>>>(s_bf, s_bf, 256, wk,
                    nullptr, kvab, 512, 256, 1, 256, nullptr, 0, 0);
            }
            hipMemsetAsync(kvb, 0, (524288 + 16384) * 4, stream);
            lft_kv_kernel<<<dim3(KV_NCH, 8, 64), blk, 0, stream>>>(kvab, tls, mts, kvb, ksb);
            lft_kvconv_kernel<<<64, blk, 0, stream>>>(kvb, ksb, kvt);
            lft_msg_kernel<<<dim3(MSG_NCH, 8, 8), blk, 0, stream>>>(qb_bf, kvt, tlx, mtx, msg_bf);
            // msg = LN(msg @ Wm)*g1+b1 -- fused GEMM+LN, bf16 in-place
            lft_gemm_ln<<<600, blk, 0, stream>>>(msg_bf, wm, 256, g1p, b1p,
                                                 nullptr, nullptr, nullptr, msg_bf);
            // hid = relu([x|msg]@W1) bf16
            lft_mfma_gemm<<<gB, blk, 0, stream>>>(x_bf, msg_bf, 256, w1,
                nullptr, hid_bf, 512, 512, 2, 512, nullptr, 0, 0);
            // out = valid ? resid + LN(hid@W2) : resid -- fused GEMM+LN+resid
            lft_gemm_ln<<<600, blk, 0, stream>>>(hid_bf, w2, 512, g2p, b2p,
                                                 residp, clsx, outFp, x_bf);
        };

        const float* ra = (li == 0) ? feat0 : fa;
        const float* rb = (li == 0) ? feat1 : fb;
        float* oa = (li == 3) ? out : fa;
        float* ob = (li == 3) ? (out + FSZ) : fb;

        if ((li & 1) == 0) {           // self-self
            call(fa_bf, fa_bf, cls0, tl0, meta,       tl0, meta,       ra, oa);
            call(fb_bf, fb_bf, cls1, tl1, meta + 128, tl1, meta + 128, rb, ob);
        } else {                       // cross-self: x=feat0 iterates tl0, gathers tl1
            call(fa_bf, fb_bf, cls0, tl0, meta,       tl1, meta + 128, ra, oa);
            call(fb_bf, fa_bf, cls1, tl1, meta + 128, tl0, meta,      rb, ob);
        }
    }
}

// Round 16
// 1580.960 us; speedup vs baseline: 1.0089x; 1.0089x over previous
//
#include <hip/hip_runtime.h>
#include <math.h>

#define NPROTO 8
#define KV_NCH 4
#define MSG_NCH 8
#define KVSTRIDE 540672L   // per-side kv scratch: 524288 (kv) + 16384 (ksum) floats

typedef __attribute__((ext_vector_type(8))) short short8;
typedef __attribute__((ext_vector_type(4))) float floatx4;

static __device__ __forceinline__ ushort f2b(float f) {
    unsigned u = __builtin_bit_cast(unsigned, f);
    unsigned r = (u + 0x7fffu + ((u >> 16) & 1u)) >> 16;
    return (ushort)r;
}

static __device__ __forceinline__ float b2f(ushort u) {
    return __builtin_bit_cast(float, ((unsigned)u) << 16);
}

typedef __attribute__((address_space(1))) void gvoid;
typedef __attribute__((address_space(3))) void lvoid;

static __device__ __forceinline__ void gload_lds16(const ushort* g, ushort* l) {
    __builtin_amdgcn_global_load_lds((gvoid*)(void*)g, (lvoid*)l, 16, 0, 0);
}

// ---------------- prototype projection / argmax-class kernel ----------------
__global__ __launch_bounds__(256) void lft_class_kernel(
    const float* __restrict__ f0wo, const float* __restrict__ f1wo,
    const int* __restrict__ mask0, const int* __restrict__ mask1,
    const float* __restrict__ proto,
    float* out, int* cls0, int* cls1)
{
    __shared__ float pr[2048];
    int t = threadIdx.x;
    *(float4*)&pr[t * 4]        = *(const float4*)&proto[t * 4];
    *(float4*)&pr[1024 + t * 4] = *(const float4*)&proto[1024 + t * 4];
    __syncthreads();
    int wave = t >> 6, lane = t & 63;
    long token = (long)blockIdx.x * 4 + wave;
    const float* fsrc; const int* msrc; float* fpout; float* clsout; int* clsarr; long tok;
    if (token < 38400) {
        tok = token; fsrc = f0wo; msrc = mask0;
        fpout = out + 19737600L; clsout = out + 19660800L; clsarr = cls0;
    } else {
        tok = token - 38400; fsrc = f1wo; msrc = mask1;
        fpout = out + 20044800L; clsout = out + 19699200L; clsarr = cls1;
    }
    float4 f = *(const float4*)&fsrc[tok * 256 + lane * 4];
    float s[NPROTO];
#pragma unroll
    for (int p = 0; p < NPROTO; p++) {
        float4 pv = *(const float4*)&pr[p * 256 + lane * 4];
        s[p] = f.x * pv.x + f.y * pv.y + f.z * pv.z + f.w * pv.w;
    }
    float k0_ = (lane & 1) ? s[4] : s[0], d0 = (lane & 1) ? s[0] : s[4];
    float k1_ = (lane & 1) ? s[5] : s[1], d1 = (lane & 1) ? s[1] : s[5];
    float k2_ = (lane & 1) ? s[6] : s[2], d2 = (lane & 1) ? s[2] : s[6];
    float k3_ = (lane & 1) ? s[7] : s[3], d3 = (lane & 1) ? s[3] : s[7];
    float w0 = k0_ + __shfl_xor(d0, 1, 64);
    float w1 = k1_ + __shfl_xor(d1, 1, 64);
    float w2 = k2_ + __shfl_xor(d2, 1, 64);
    float w3 = k3_ + __shfl_xor(d3, 1, 64);
    float u0k = (lane & 2) ? w2 : w0, u0d = (lane & 2) ? w0 : w2;
    float u1k = (lane & 2) ? w3 : w1, u1d = (lane & 2) ? w1 : w3;
    float x0 = u0k + __shfl_xor(u0d, 2, 64);
    float x1 = u1k + __shfl_xor(u1d, 2, 64);
    float yk = (lane & 4) ? x1 : x0, yd = (lane & 4) ? x0 : x1;
    float sc = yk + __shfl_xor(yd, 4, 64);
    sc += __shfl_xor(sc, 8, 64);
    sc += __shfl_xor(sc, 16, 64);
    sc += __shfl_xor(sc, 32, 64);
    int p = ((lane & 1) << 2) | (lane & 2) | ((lane >> 2) & 1);
    if (lane < 8) fpout[tok * 8 + p] = sc;
    float bv = sc; int bi = p;
#pragma unroll
    for (int o = 1; o < 8; o <<= 1) {
        float ov = __shfl_xor(bv, o, 64);
        int oi = __shfl_xor(bi, o, 64);
        if (ov > bv || (ov == bv && oi < bi)) { bv = ov; bi = oi; }
    }
    if (lane == 0) {
        clsout[tok] = (float)bi;
        clsarr[tok] = msrc[tok] ? bi : -1;
    }
}

// ---------------- counting sort of tokens by (batch,class) -------------------
__global__ __launch_bounds__(256) void lft_sort_kernel(
    const int* __restrict__ cls0, const int* __restrict__ cls1,
    int* tl0, int* tl1, int* meta)
{
    int g = blockIdx.x; int L = g >> 3, b = g & 7;
    const int* cls = (L ? cls1 : cls0) + b * 4800;
    int* tl = (L ? tl1 : tl0) + b * 4800;
    int* mt = meta + (L * 8 + b) * 16;
    __shared__ int cnt[8], base[8], pos[8];
    int t = threadIdx.x;
    if (t < 8) cnt[t] = 0;
    __syncthreads();
    for (int tok = t; tok < 4800; tok += 256) {
        int c = cls[tok];
        if (c >= 0) atomicAdd(&cnt[c], 1);
    }
    __syncthreads();
    if (t == 0) {
        int s = 0;
        for (int c = 0; c < 8; c++) { base[c] = s; pos[c] = s; s += cnt[c]; }
    }
    __syncthreads();
    if (t < 8) { mt[t * 2] = base[t]; mt[t * 2 + 1] = cnt[t]; }
    for (int tok = t; tok < 4800; tok += 256) {
        int c = cls[tok];
        if (c >= 0) { int p = atomicAdd(&pos[c], 1); tl[p] = tok; }
    }
}

// ---------------- weight convert + transpose: Wt[n*K+k] = bf16(W[k*N+n]) ----
__global__ __launch_bounds__(256) void lft_wconv_kernel(
    const float* W0, const float* W1p, const float* W2p, const float* W3p,
    int K, int N, int nTypes, ushort* dst)
{
    int z = blockIdx.z;
    int li = z / nTypes, mi = z % nTypes;
    const float* srcs[4] = {W0, W1p, W2p, W3p};
    const float* src = srcs[mi] + (size_t)li * K * N;
    ushort* outp = dst + (size_t)z * K * N;
    __shared__ float tile[32][33];
    int k0 = blockIdx.x * 32, n0 = blockIdx.y * 32;
    int t = threadIdx.x;
    int r = t >> 3, c4 = (t & 7) << 2;
    float4 v = *(const float4*)&src[(size_t)(k0 + r) * N + n0 + c4];
    tile[r][c4] = v.x; tile[r][c4 + 1] = v.y; tile[r][c4 + 2] = v.z; tile[r][c4 + 3] = v.w;
    __syncthreads();
    ushort4 o;
    o.x = f2b(tile[c4 + 0][r]);
    o.y = f2b(tile[c4 + 1][r]);
    o.z = f2b(tile[c4 + 2][r]);
    o.w = f2b(tile[c4 + 3][r]);
    *(ushort4*)&outp[(size_t)(n0 + r) * K + k0 + c4] = o;
}

// ---------------- bf16 cast of feat0/feat1 (shadows only) ----------------
__global__ __launch_bounds__(256) void lft_cast_kernel(
    const float* __restrict__ f0, const float* __restrict__ f1,
    ushort* fab, ushort* fbb)
{
    long idx = ((long)blockIdx.x * 256 + threadIdx.x) * 4;
    const float* src; ushort* db; long o;
    if (idx < 9830400L) { src = f0; db = fab; o = idx; }
    else                { src = f1; db = fbb; o = idx - 9830400L; }
    float4 v = *(const float4*)&src[o];
    ushort4 u; u.x = f2b(v.x); u.y = f2b(v.y); u.z = f2b(v.z); u.w = f2b(v.w);
    *(ushort4*)&db[o] = u;
}

// ---------------- bf16 MFMA GEMM, 2-phase pipelined: C = act([A0|A1] @ Wt^T) -
__global__ __launch_bounds__(256) void lft_mfma_gemm(
    const ushort* __restrict__ A0, const ushort* __restrict__ A1, int kSplit,
    const ushort* __restrict__ Wt,
    float* Cf, ushort* Cb, int N, int K, int act, int actSplit,
    ushort* Cb2, int N2, int colSplit)
{
    __shared__ ushort As[2][128 * 32];
    __shared__ ushort Bs[2][128 * 32];
    int t = threadIdx.x;
    int nbx = gridDim.x;
    int nwg = nbx * gridDim.y;
    int orig = blockIdx.y * nbx + blockIdx.x;
    int q8 = nwg >> 3;
    int swz = (nwg & 7) ? orig : ((orig & 7) * q8 + (orig >> 3));
    int bx = swz % nbx, by = swz / nbx;
    int m0 = by << 7;
    int n0 = bx << 7;
    int wave = t >> 6, lane = t & 63;
    int wm = wave >> 1, wn = wave & 1;
    int l16 = lane & 15, quad = lane >> 4;
    int r = t >> 2;
    int cu = (t & 3) << 3;
    int fso = (((t & 3) ^ ((r ^ (r >> 2)) & 3)) << 3);
    floatx4 acc[4][4] = {};

    auto stage = [&](int buf, int k0) {
        const ushort* Asrc; int kcol, ldA;
        if (k0 < kSplit) { Asrc = A0; kcol = k0;          ldA = kSplit; }
        else             { Asrc = A1; kcol = k0 - kSplit; ldA = K - kSplit; }
        gload_lds16(&Asrc[(size_t)(m0 + r) * ldA + kcol + fso],      &As[buf][r * 32 + cu]);
        gload_lds16(&Asrc[(size_t)(m0 + r + 64) * ldA + kcol + fso], &As[buf][(r + 64) * 32 + cu]);
        gload_lds16(&Wt[(size_t)(n0 + r) * K + k0 + fso],            &Bs[buf][r * 32 + cu]);
        gload_lds16(&Wt[(size_t)(n0 + r + 64) * K + k0 + fso],       &Bs[buf][(r + 64) * 32 + cu]);
    };

    int qs = ((quad ^ ((l16 ^ (l16 >> 2)) & 3)) << 3);
    stage(0, 0);
    int cur = 0;
    for (int k0 = 0; k0 < K; k0 += 32) {
        if (k0 + 32 < K) {
            stage(cur ^ 1, k0 + 32);
            asm volatile("s_waitcnt vmcnt(4)" ::: "memory");
        } else {
            asm volatile("s_waitcnt vmcnt(0)" ::: "memory");
        }
        __builtin_amdgcn_s_barrier();
        short8 af[4], bfr[4];
#pragma unroll
        for (int i = 0; i < 4; i++) {
            af[i]  = *(const short8*)&As[cur][(wm * 64 + i * 16 + l16) * 32 + qs];
            bfr[i] = *(const short8*)&Bs[cur][(wn * 64 + i * 16 + l16) * 32 + qs];
        }
#pragma unroll
        for (int i = 0; i < 4; i++)
#pragma unroll
            for (int j = 0; j < 4; j++)
                acc[i][j] = __builtin_amdgcn_mfma_f32_16x16x32_bf16(bfr[j], af[i], acc[i][j], 0, 0, 0);
        asm volatile("" ::: "memory");
        __builtin_amdgcn_s_barrier();
        cur ^= 1;
    }
    int effAct = (n0 >= actSplit) ? 0 : act;
    float* Cfp = Cf;
    ushort* Cbp = Cb;
    int ldC = N, cb0 = n0;
    if (Cb2 && n0 >= colSplit) { Cbp = Cb2; Cfp = nullptr; ldC = N2; cb0 = n0 - colSplit; }
#pragma unroll
    for (int i = 0; i < 4; i++) {
        long rowb = m0 + wm * 64 + i * 16 + l16;
#pragma unroll
        for (int j = 0; j < 4; j++) {
            int colb = cb0 + wn * 64 + j * 16 + quad * 4;
            float v0 = acc[i][j][0], v1 = acc[i][j][1], v2 = acc[i][j][2], v3 = acc[i][j][3];
            if (effAct == 1) {
                v0 = v0 > 0.f ? v0 + 1.f : __expf(v0);
                v1 = v1 > 0.f ? v1 + 1.f : __expf(v1);
                v2 = v2 > 0.f ? v2 + 1.f : __expf(v2);
                v3 = v3 > 0.f ? v3 + 1.f : __expf(v3);
            } else if (effAct == 2) {
                v0 = fmaxf(v0, 0.f); v1 = fmaxf(v1, 0.f);
                v2 = fmaxf(v2, 0.f); v3 = fmaxf(v3, 0.f);
            }
            if (Cfp) {
                float4 f4; f4.x = v0; f4.y = v1; f4.z = v2; f4.w = v3;
                *(float4*)&Cfp[rowb * ldC + colb] = f4;
            }
            if (Cbp) {
                ushort4 u4;
                u4.x = f2b(v0); u4.y = f2b(v1); u4.z = f2b(v2); u4.w = f2b(v3);
                *(ushort4*)&Cbp[rowb * ldC + colb] = u4;
            }
        }
    }
}

// ---------------- fused GEMM (N=256 full-row) + LayerNorm epilogue (r12) -----
__global__ __launch_bounds__(256) void lft_gemm_ln(
    const ushort* __restrict__ A, const ushort* __restrict__ Wt, int K,
    const float* __restrict__ g, const float* __restrict__ bb,
    const float* __restrict__ resid, const int* __restrict__ cls,
    float* outF, ushort* __restrict__ outB)
{
    __shared__ ushort As[2][64 * 32];
    __shared__ ushort Bs[2][256 * 32];
    __shared__ float red[4][64][2];
    int t = threadIdx.x;
    long m0 = (long)blockIdx.x << 6;
    int wave = t >> 6, lane = t & 63;
    int wn = wave;
    int l16 = lane & 15, quad = lane >> 4;
    int r = t >> 2;
    int cu = (t & 3) << 3;
    int fso = (((t & 3) ^ ((r ^ (r >> 2)) & 3)) << 3);
    floatx4 acc[4][4] = {};

    auto stage = [&](int buf, int k0) {
        gload_lds16(&A[(m0 + r) * K + k0 + fso], &As[buf][r * 32 + cu]);
#pragma unroll
        for (int s = 0; s < 4; s++)
            gload_lds16(&Wt[(size_t)(s * 64 + r) * K + k0 + fso],
                        &Bs[buf][(s * 64 + r) * 32 + cu]);
    };

    int qs = ((quad ^ ((l16 ^ (l16 >> 2)) & 3)) << 3);
    stage(0, 0);
    int cur = 0;
    for (int k0 = 0; k0 < K; k0 += 32) {
        if (k0 + 32 < K) {
            stage(cur ^ 1, k0 + 32);
            asm volatile("s_waitcnt vmcnt(5)" ::: "memory");
        } else {
            asm volatile("s_waitcnt vmcnt(0)" ::: "memory");
        }
        __builtin_amdgcn_s_barrier();
        short8 af[4], bfr[4];
#pragma unroll
        for (int i = 0; i < 4; i++) {
            af[i]  = *(const short8*)&As[cur][(i * 16 + l16) * 32 + qs];
            bfr[i] = *(const short8*)&Bs[cur][(wn * 64 + i * 16 + l16) * 32 + qs];
        }
#pragma unroll
        for (int i = 0; i < 4; i++)
#pragma unroll
            for (int j = 0; j < 4; j++)
                acc[i][j] = __builtin_amdgcn_mfma_f32_16x16x32_bf16(bfr[j], af[i], acc[i][j], 0, 0, 0);
        asm volatile("" ::: "memory");
        __builtin_amdgcn_s_barrier();
        cur ^= 1;
    }
#pragma unroll
    for (int i = 0; i < 4; i++) {
        float s = 0.f, sq = 0.f;
#pragma unroll
        for (int j = 0; j < 4; j++)
#pragma unroll
            for (int rr = 0; rr < 4; rr++) { float v = acc[i][j][rr]; s += v; sq += v * v; }
        s  += __shfl_xor(s, 16, 64);  sq += __shfl_xor(sq, 16, 64);
        s  += __shfl_xor(s, 32, 64);  sq += __shfl_xor(sq, 32, 64);
        if (quad == 0) {
            int rl = i * 16 + l16;
            red[wn][rl][0] = s;
            red[wn][rl][1] = sq;
        }
    }
    __syncthreads();
#pragma unroll
    for (int i = 0; i < 4; i++) {
        int rl = i * 16 + l16;
        long row = m0 + rl;
        float tsum = red[0][rl][0] + red[1][rl][0] + red[2][rl][0] + red[3][rl][0];
        float tsq  = red[0][rl][1] + red[1][rl][1] + red[2][rl][1] + red[3][rl][1];
        float mean = tsum * (1.0f / 256.0f);
        float var  = tsq * (1.0f / 256.0f) - mean * mean;
        float rsq  = rsqrtf(var + 1e-5f);
        bool keep = true;
        if (cls) keep = (cls[row] >= 0);
#pragma unroll
        for (int j = 0; j < 4; j++) {
            int col = wn * 64 + j * 16 + quad * 4;
            float4 gv = *(const float4*)&g[col];
            float4 bv = *(const float4*)&bb[col];
            float y0 = (acc[i][j][0] - mean) * rsq * gv.x + bv.x;
            float y1 = (acc[i][j][1] - mean) * rsq * gv.y + bv.y;
            float y2 = (acc[i][j][2] - mean) * rsq * gv.z + bv.z;
            float y3 = (acc[i][j][3] - mean) * rsq * gv.w + bv.w;
            if (resid) {
                float4 xr = *(const float4*)&resid[row * 256 + col];
                if (keep) { y0 += xr.x; y1 += xr.y; y2 += xr.z; y3 += xr.w; }
                else      { y0 = xr.x;  y1 = xr.y;  y2 = xr.z;  y3 = xr.w; }
            }
            if (outF) {
                float4 f4; f4.x = y0; f4.y = y1; f4.z = y2; f4.w = y3;
                *(float4*)&outF[row * 256 + col] = f4;
            }
            ushort4 u4;
            u4.x = f2b(y0); u4.y = f2b(y1); u4.z = f2b(y2); u4.w = f2b(y3);
            *(ushort4*)&outB[row * 256 + col] = u4;
        }
    }
}

// ---------------- per-class KV / Ksum reduction, SIDE-MERGED -----------------
// z: side = z>>6 (0/1), b = (z&63)>>3, h = z&7. Per-side ptr sets.
__global__ __launch_bounds__(256) void lft_kv_kernel(
    const ushort* kvabA, const ushort* kvabB,
    const int* tlA, const int* tlB,
    const int* mtA, const int* mtB, float* kvbase)
{
    int z = blockIdx.z;
    int side = z >> 6, zz = z & 63;
    int chunk = blockIdx.x, c = blockIdx.y;
    int b = zz >> 3, h = zz & 7;
    const ushort* kvab = side ? kvabB : kvabA;
    const int* tlist = side ? tlB : tlA;
    const int* meta  = side ? mtB : mtA;
    float* kv = kvbase + (long)side * KVSTRIDE;
    float* ksum = kv + 524288;
    int off = meta[(b * 8 + c) * 2], n = meta[(b * 8 + c) * 2 + 1];
    int per = (n + KV_NCH - 1) / KV_NCH;
    int s0 = chunk * per;
    int s1 = min(s0 + per, n);
    if (s0 >= s1) return;
    const int* tl = tlist + b * 4800 + off;
    int t = threadIdx.x;
    __shared__ float kb[8][32];
    __shared__ float vb[8][32];
    int od = t >> 3, oe = (t & 7) << 2;
    int lt = t >> 5, ld = t & 31;
    float a0 = 0.f, a1 = 0.f, a2 = 0.f, a3 = 0.f, ak = 0.f;
    for (int s = s0; s < s1; s += 8) {
        float kval = 0.f, vval = 0.f;
        if (s + lt < s1) {
            int tok = tl[s + lt];
            long bse = ((long)b * 4800 + tok) * 512 + h * 32 + ld;
            kval = b2f(kvab[bse]);
            vval = b2f(kvab[bse + 256]);
        }
        __syncthreads();
        kb[lt][ld] = kval;
        vb[lt][ld] = vval;
        __syncthreads();
#pragma unroll
        for (int j = 0; j < 8; j++) {
            float kd = kb[j][od];
            float4 vv = *(const float4*)&vb[j][oe];
            a0 += kd * vv.x; a1 += kd * vv.y; a2 += kd * vv.z; a3 += kd * vv.w;
            ak += kd;
        }
    }
    float* dst = kv + (((long)(b * NPROTO + c) * 8 + h) << 10) + od * 32 + oe;
    atomicAdd(dst + 0, a0);
    atomicAdd(dst + 1, a1);
    atomicAdd(dst + 2, a2);
    atomicAdd(dst + 3, a3);
    if ((t & 7) == 0)
        atomicAdd(ksum + (((long)(b * NPROTO + c) * 8 + h) << 5) + od, ak);
}

// ---------------- kv fp32 -> bf16 B-layout, SIDE-MERGED ----------------------
__global__ __launch_bounds__(256) void lft_kvconv_kernel(
    const float* kvbase, ushort* kvtA, ushort* kvtB)
{
    int idx = blockIdx.x;
    int side = idx >> 6, bc = idx & 63;
    const float* kvb = kvbase + (long)side * KVSTRIDE;
    const float* ksb = kvb + 524288;
    ushort* kvt = side ? kvtB : kvtA;
    int t = threadIdx.x;
    int h = t >> 5, d = t & 31;
    const float* kvsrc = kvb + ((long)bc * 8 + h) * 1024;
    const float* kssrc = ksb + ((long)bc * 8 + h) * 32;
    ushort* dst = kvt + ((long)bc * 8 + h) * 1536;
#pragma unroll
    for (int e = 0; e < 32; e++) dst[e * 32 + d] = f2b(kvsrc[d * 32 + e]);
    dst[32 * 32 + d] = f2b(kssrc[d]);
#pragma unroll
    for (int e = 33; e < 48; e++) dst[e * 32 + d] = 0;
}

// ---------------- msg via MFMA, SIDE-MERGED ----------------------------------
// z: side = z>>3, b = z&7.
__global__ __launch_bounds__(256) void lft_msg_kernel(
    const ushort* qA, const ushort* qB,
    const ushort* kvtA, const ushort* kvtB,
    const int* tlA, const int* tlB, const int* mtA, const int* mtB,
    ushort* msgA_, ushort* msgB_)
{
    int z = blockIdx.z;
    int side = z >> 3, b = z & 7;
    int chunk = blockIdx.x, c = blockIdx.y;
    const ushort* pq = side ? qB : qA;
    const ushort* kvt = side ? kvtB : kvtA;
    const int* tlist = side ? tlB : tlA;
    const int* meta  = side ? mtB : mtA;
    ushort* msg = side ? msgB_ : msgA_;
    int off = meta[(b * 8 + c) * 2], n = meta[(b * 8 + c) * 2 + 1];
    int per = (n + MSG_NCH - 1) / MSG_NCH;
    int s0 = chunk * per, s1 = min(s0 + per, n);
    if (s0 >= s1) return;
    const int* tl = tlist + b * 4800 + off;
    int t = threadIdx.x;
    int wave = t >> 6, lane = t & 63;
    int l16 = lane & 15, quad = lane >> 4;
    int bc = b * 8 + c;
    short8 bfr[2][3];
#pragma unroll
    for (int hh = 0; hh < 2; hh++) {
        int h = wave * 2 + hh;
        const ushort* kb = kvt + ((long)bc * 8 + h) * 1536;
#pragma unroll
        for (int nt = 0; nt < 3; nt++)
            bfr[hh][nt] = *(const short8*)&kb[(nt * 16 + l16) * 32 + quad * 8];
    }
    for (int s = s0; s < s1; s += 16) {
        int ia = min(s + l16, s1 - 1);
        int tokA = tl[ia];
        long rowA = (long)b * 4800 + tokA;
#pragma unroll
        for (int hh = 0; hh < 2; hh++) {
            int h = wave * 2 + hh;
            short8 a = *(const short8*)&pq[rowA * 256 + h * 32 + quad * 8];
            floatx4 n0 = {}, n1 = {}, dd = {};
            n0 = __builtin_amdgcn_mfma_f32_16x16x32_bf16(a, bfr[hh][0], n0, 0, 0, 0);
            n1 = __builtin_amdgcn_mfma_f32_16x16x32_bf16(a, bfr[hh][1], n1, 0, 0, 0);
            dd = __builtin_amdgcn_mfma_f32_16x16x32_bf16(a, bfr[hh][2], dd, 0, 0, 0);
#pragma unroll
            for (int r = 0; r < 4; r++) {
                int rowi = s + quad * 4 + r;
                float den = __shfl(dd[r], lane & 48, 64);
                float inv = 1.f / (den + 1e-6f);
                int tokr = __shfl(tokA, quad * 4 + r, 64);
                if (rowi < s1) {
                    long base = ((long)b * 4800 + tokr) * 256 + h * 32;
                    msg[base + l16]      = f2b(n0[r] * inv);
                    msg[base + 16 + l16] = f2b(n1[r] * inv);
                }
            }
        }
    }
}

extern "C" void kernel_launch(void* const* d_in, const int* in_sizes, int n_in,
                              void* d_out, int out_size, void* d_ws, size_t ws_size,
                              hipStream_t stream)
{
    (void)in_sizes; (void)n_in; (void)out_size; (void)ws_size;
    const float* feat0 = (const float*)d_in[0];
    const float* feat1 = (const float*)d_in[1];
    const int*   mask0 = (const int*)d_in[2];
    const int*   mask1 = (const int*)d_in[3];
    const float* f0wo  = (const float*)d_in[4];
    const float* f1wo  = (const float*)d_in[5];
    const float* proto = (const float*)d_in[6];
    const float* Wq = (const float*)d_in[7];
    const float* Wk = (const float*)d_in[8];
    const float* Wv = (const float*)d_in[9];
    const float* Wm = (const float*)d_in[10];
    const float* W1 = (const float*)d_in[11];
    const float* W2 = (const float*)d_in[12];
    const float* g1 = (const float*)d_in[13];
    const float* b1 = (const float*)d_in[14];
    const float* g2 = (const float*)d_in[15];
    const float* b2 = (const float*)d_in[16];
    float* out = (float*)d_out;
    float* ws = (float*)d_ws;

    // ---- workspace layout ----
    const long FSZ = 9830400L;               // 8*4800*256
    float* fa = ws;                          // fp32 master feat0
    float* fb = ws + FSZ;                    // fp32 master feat1
    // region R2 = [ws+2FSZ, ws+3FSZ): kvab0 (phase1) -> msg0|msg1 -> hid (late)
    // region R3 = [ws+3FSZ, ws+4FSZ): kvab1 / kvt1 (evens) -> hid
    ushort* kvab0 = (ushort*)(ws + 2 * FSZ);
    ushort* kvab1 = (ushort*)(ws + 3 * FSZ);
    ushort* msgA  = (ushort*)(ws + 2 * FSZ);        // 19.7MB (first half of R2)
    ushort* msgB  = (ushort*)(ws + 2 * FSZ) + FSZ;  // second half of R2
    ushort* hidA  = (ushort*)(ws + 3 * FSZ);        // 39.3MB (all of R3)
    ushort* hidB  = (ushort*)(ws + 2 * FSZ);        // all of R2 (after msgs dead)
    ushort* kvt1  = (ushort*)(ws + 3 * FSZ);        // evens: over dead kvab1
    ushort* ub  = (ushort*)(ws + 4 * FSZ);
    ushort* fa_bf = ub;                      // bf16 shadow of fa
    ushort* fb_bf = ub + FSZ;                // bf16 shadow of fb
    ushort* qb1   = ub + 2 * FSZ;            // side1 phi_q (evens)
    ushort* qb0   = ub + 3 * FSZ;            // side0 phi_q ; later msg1 out slot
    ushort* msg1e = ub + 3 * FSZ;            // (unused alias, kept for clarity)
    ushort* wb    = ub + 4 * FSZ;            // bf16 transposed weights
    ushort* wb1   = wb + 16 * 65536;         // W1^T per layer [512][512]
    ushort* wb2   = wb1 + 4 * 262144;        // W2^T per layer [256][512]
    ushort* kvt0  = wb2 + 4 * 131072;        // [64][8][48][32] bf16 (side0 static)
    float* kvb = (float*)(kvt0 + 786432);    // 2 x KVSTRIDE floats (kv+ksum per side)
    int* cls0 = (int*)(kvb + 2 * KVSTRIDE);
    int* cls1 = cls0 + 38400;
    int* tl0  = cls1 + 38400;
    int* tl1  = tl0 + 38400;
    int* meta = tl1 + 38400;                 // [2][8][8][2] (off,cnt)
    (void)msg1e;

    // one-time per launch
    lft_wconv_kernel<<<dim3(8, 8, 16), 256, 0, stream>>>(Wq, Wk, Wv, Wm, 256, 256, 4, wb);
    lft_wconv_kernel<<<dim3(16, 16, 4), 256, 0, stream>>>(W1, W1, W1, W1, 512, 512, 1, wb1);
    lft_wconv_kernel<<<dim3(16, 8, 4), 256, 0, stream>>>(W2, W2, W2, W2, 512, 256, 1, wb2);
    lft_cast_kernel<<<19200, 256, 0, stream>>>(feat0, feat1, fa_bf, fb_bf);
    hipMemcpyAsync(out + 20352000L, proto, 2048 * 4, hipMemcpyDeviceToDevice, stream);
    lft_class_kernel<<<19200, 256, 0, stream>>>(f0wo, f1wo, mask0, mask1, proto,
                                                out, cls0, cls1);
    lft_sort_kernel<<<16, 256, 0, stream>>>(cls0, cls1, tl0, tl1, meta);

    for (int li = 0; li < 4; li++) {
        const ushort* wq = wb + (size_t)(li * 4 + 0) * 65536;  // wq|wk|wv contig
        const ushort* wk = wb + (size_t)(li * 4 + 1) * 65536;  // wk|wv contig
        const ushort* wm = wb + (size_t)(li * 4 + 3) * 65536;
        const ushort* w1 = wb1 + (size_t)li * 262144;
        const ushort* w2 = wb2 + (size_t)li * 131072;
        const float* g1p = g1 + li * 256; const float* b1p = b1 + li * 256;
        const float* g2p = g2 + li * 256; const float* b2p = b2 + li * 256;
        dim3 blk(256);
        dim3 gA(2, 300), gB(4, 300), gQ(6, 300);

        const float* ra = (li == 0) ? feat0 : fa;
        const float* rb = (li == 0) ? feat1 : fb;
        float* oa = (li == 3) ? out : fa;
        float* ob = (li == 3) ? (out + FSZ) : fb;

        if ((li & 1) == 0) {
            // ===== self-self: merged phase1 (both sides), then phase2 x2 =====
            lft_mfma_gemm<<<gQ, blk, 0, stream>>>(fa_bf, fa_bf, 256, wq,
                nullptr, qb0, 256, 256, 1, 512, kvab0, 512, 256);
            lft_mfma_gemm<<<gQ, blk, 0, stream>>>(fb_bf, fb_bf, 256, wq,
                nullptr, qb1, 256, 256, 1, 512, kvab1, 512, 256);
            hipMemsetAsync(kvb, 0, 2 * KVSTRIDE * 4, stream);
            lft_kv_kernel<<<dim3(KV_NCH, 8, 128), blk, 0, stream>>>(
                kvab0, kvab1, tl0, tl1, meta, meta + 128, kvb);
            lft_kvconv_kernel<<<128, blk, 0, stream>>>(kvb, kvt0, kvt1);
            lft_msg_kernel<<<dim3(MSG_NCH, 8, 16), blk, 0, stream>>>(
                qb0, qb1, kvt0, kvt1, tl0, tl1, meta, meta + 128, msgA, msgB);
            // phase2 side0 (hid over R3: kvt1 consumed by msg above)
            lft_gemm_ln<<<600, blk, 0, stream>>>(msgA, wm, 256, g1p, b1p,
                                                 nullptr, nullptr, nullptr, msgA);
            lft_mfma_gemm<<<gB, blk, 0, stream>>>(fa_bf, msgA, 256, w1,
                nullptr, hidA, 512, 512, 2, 512, nullptr, 0, 0);
            lft_gemm_ln<<<600, blk, 0, stream>>>(hidA, w2, 512, g2p, b2p,
                                                 ra, cls0, oa, fa_bf);
            // phase2 side1 (hid reuses R3; msgB lives in R2 second half)
            lft_gemm_ln<<<600, blk, 0, stream>>>(msgB, wm, 256, g1p, b1p,
                                                 nullptr, nullptr, nullptr, msgB);
            lft_mfma_gemm<<<gB, blk, 0, stream>>>(fb_bf, msgB, 256, w1,
                nullptr, hidA, 512, 512, 2, 512, nullptr, 0, 0);
            lft_gemm_ln<<<600, blk, 0, stream>>>(hidA, w2, 512, g2p, b2p,
                                                 rb, cls1, ob, fb_bf);
        } else {
            // ===== cross-self: sequential sides (side1 depends on updated side0)
            // side0: x=fa iterates tl0/meta; src=fb gathered via tl1/meta+128
            lft_mfma_gemm<<<gA, blk, 0, stream>>>(fa_bf, fa_bf, 256, wq,
                nullptr, qb0, 256, 256, 1, 256, nullptr, 0, 0);
            lft_mfma_gemm<<<gB, blk, 0, stream>>>(fb_bf, fb_bf, 256, wk,
                nullptr, kvab0, 512, 256, 1, 256, nullptr, 0, 0);
            hipMemsetAsync(kvb, 0, KVSTRIDE * 4, stream);
            lft_kv_kernel<<<dim3(KV_NCH, 8, 64), blk, 0, stream>>>(
                kvab0, nullptr, tl1, nullptr, meta + 128, nullptr, kvb);
            lft_kvconv_kernel<<<64, blk, 0, stream>>>(kvb, kvt0, nullptr);
            lft_msg_kernel<<<dim3(MSG_NCH, 8, 8), blk, 0, stream>>>(
                qb0, nullptr, kvt0, nullptr, tl0, nullptr, meta, nullptr, msgA, nullptr);
            lft_gemm_ln<<<600, blk, 0, stream>>>(msgA, wm, 256, g1p, b1p,
                                                 nullptr, nullptr, nullptr, msgA);
            lft_mfma_gemm<<<gB, blk, 0, stream>>>(fa_bf, msgA, 256, w1,
                nullptr, hidA, 512, 512, 2, 512, nullptr, 0, 0);
            lft_gemm_ln<<<600, blk, 0, stream>>>(hidA, w2, 512, g2p, b2p,
                                                 ra, cls0, oa, fa_bf);
            // side1: x=fb iterates tl1/meta+128; src=UPDATED fa via tl0/meta
            lft_mfma_gemm<<<gA, blk, 0, stream>>>(fb_bf, fb_bf, 256, wq,
                nullptr, qb0, 256, 256, 1, 256, nullptr, 0, 0);
            lft_mfma_gemm<<<gB, blk, 0, stream>>>(fa_bf, fa_bf, 256, wk,
                nullptr, kvab0, 512, 256, 1, 256, nullptr, 0, 0);
            hipMemsetAsync(kvb, 0, KVSTRIDE * 4, stream);
            lft_kv_kernel<<<dim3(KV_NCH, 8, 64), blk, 0, stream>>>(
                kvab0, nullptr, tl0, nullptr, meta, nullptr, kvb);
            lft_kvconv_kernel<<<64, blk, 0, stream>>>(kvb, kvt0, nullptr);
            lft_msg_kernel<<<dim3(MSG_NCH, 8, 8), blk, 0, stream>>>(
                qb0, nullptr, kvt0, nullptr, tl1, nullptr, meta + 128, nullptr, msgA, nullptr);
            lft_gemm_ln<<<600, blk, 0, stream>>>(msgA, wm, 256, g1p, b1p,
                                                 nullptr, nullptr, nullptr, msgA);
            lft_mfma_gemm<<<gB, blk, 0, stream>>>(fb_bf, msgA, 256, w1,
                nullptr, hidA, 512, 512, 2, 512, nullptr, 0, 0);
            lft_gemm_ln<<<600, blk, 0, stream>>>(hidA, w2, 512, g2p, b2p,
                                                 rb, cls1, ob, fb_bf);
        }
    }
}

// Round 17
// 1545.472 us; speedup vs baseline: 1.0320x; 1.0230x over previous
//
#include <hip/hip_runtime.h>
#include <math.h>

#define NPROTO 8
#define KV_NCH 4
#define MSG_NCH 8
#define KVSTRIDE 540672L   // per-side kv scratch: 524288 (kv) + 16384 (ksum) floats

typedef __attribute__((ext_vector_type(8))) short short8;
typedef __attribute__((ext_vector_type(4))) float floatx4;

static __device__ __forceinline__ ushort f2b(float f) {
    unsigned u = __builtin_bit_cast(unsigned, f);
    unsigned r = (u + 0x7fffu + ((u >> 16) & 1u)) >> 16;
    return (ushort)r;
}

static __device__ __forceinline__ float b2f(ushort u) {
    return __builtin_bit_cast(float, ((unsigned)u) << 16);
}

typedef __attribute__((address_space(1))) void gvoid;
typedef __attribute__((address_space(3))) void lvoid;

static __device__ __forceinline__ void gload_lds16(const ushort* g, ushort* l) {
    __builtin_amdgcn_global_load_lds((gvoid*)(void*)g, (lvoid*)l, 16, 0, 0);
}

// ---------------- prototype projection / argmax-class kernel ----------------
__global__ __launch_bounds__(256) void lft_class_kernel(
    const float* __restrict__ f0wo, const float* __restrict__ f1wo,
    const int* __restrict__ mask0, const int* __restrict__ mask1,
    const float* __restrict__ proto,
    float* out, int* cls0, int* cls1)
{
    __shared__ float pr[2048];
    int t = threadIdx.x;
    *(float4*)&pr[t * 4]        = *(const float4*)&proto[t * 4];
    *(float4*)&pr[1024 + t * 4] = *(const float4*)&proto[1024 + t * 4];
    __syncthreads();
    int wave = t >> 6, lane = t & 63;
    long token = (long)blockIdx.x * 4 + wave;
    const float* fsrc; const int* msrc; float* fpout; float* clsout; int* clsarr; long tok;
    if (token < 38400) {
        tok = token; fsrc = f0wo; msrc = mask0;
        fpout = out + 19737600L; clsout = out + 19660800L; clsarr = cls0;
    } else {
        tok = token - 38400; fsrc = f1wo; msrc = mask1;
        fpout = out + 20044800L; clsout = out + 19699200L; clsarr = cls1;
    }
    float4 f = *(const float4*)&fsrc[tok * 256 + lane * 4];
    float s[NPROTO];
#pragma unroll
    for (int p = 0; p < NPROTO; p++) {
        float4 pv = *(const float4*)&pr[p * 256 + lane * 4];
        s[p] = f.x * pv.x + f.y * pv.y + f.z * pv.z + f.w * pv.w;
    }
    float k0_ = (lane & 1) ? s[4] : s[0], d0 = (lane & 1) ? s[0] : s[4];
    float k1_ = (lane & 1) ? s[5] : s[1], d1 = (lane & 1) ? s[1] : s[5];
    float k2_ = (lane & 1) ? s[6] : s[2], d2 = (lane & 1) ? s[2] : s[6];
    float k3_ = (lane & 1) ? s[7] : s[3], d3 = (lane & 1) ? s[3] : s[7];
    float w0 = k0_ + __shfl_xor(d0, 1, 64);
    float w1 = k1_ + __shfl_xor(d1, 1, 64);
    float w2 = k2_ + __shfl_xor(d2, 1, 64);
    float w3 = k3_ + __shfl_xor(d3, 1, 64);
    float u0k = (lane & 2) ? w2 : w0, u0d = (lane & 2) ? w0 : w2;
    float u1k = (lane & 2) ? w3 : w1, u1d = (lane & 2) ? w1 : w3;
    float x0 = u0k + __shfl_xor(u0d, 2, 64);
    float x1 = u1k + __shfl_xor(u1d, 2, 64);
    float yk = (lane & 4) ? x1 : x0, yd = (lane & 4) ? x0 : x1;
    float sc = yk + __shfl_xor(yd, 4, 64);
    sc += __shfl_xor(sc, 8, 64);
    sc += __shfl_xor(sc, 16, 64);
    sc += __shfl_xor(sc, 32, 64);
    int p = ((lane & 1) << 2) | (lane & 2) | ((lane >> 2) & 1);
    if (lane < 8) fpout[tok * 8 + p] = sc;
    float bv = sc; int bi = p;
#pragma unroll
    for (int o = 1; o < 8; o <<= 1) {
        float ov = __shfl_xor(bv, o, 64);
        int oi = __shfl_xor(bi, o, 64);
        if (ov > bv || (ov == bv && oi < bi)) { bv = ov; bi = oi; }
    }
    if (lane == 0) {
        clsout[tok] = (float)bi;
        clsarr[tok] = msrc[tok] ? bi : -1;
    }
}

// ---------------- counting sort of tokens by (batch,class) -------------------
__global__ __launch_bounds__(256) void lft_sort_kernel(
    const int* __restrict__ cls0, const int* __restrict__ cls1,
    int* tl0, int* tl1, int* meta)
{
    int g = blockIdx.x; int L = g >> 3, b = g & 7;
    const int* cls = (L ? cls1 : cls0) + b * 4800;
    int* tl = (L ? tl1 : tl0) + b * 4800;
    int* mt = meta + (L * 8 + b) * 16;
    __shared__ int cnt[8], base[8], pos[8];
    int t = threadIdx.x;
    if (t < 8) cnt[t] = 0;
    __syncthreads();
    for (int tok = t; tok < 4800; tok += 256) {
        int c = cls[tok];
        if (c >= 0) atomicAdd(&cnt[c], 1);
    }
    __syncthreads();
    if (t == 0) {
        int s = 0;
        for (int c = 0; c < 8; c++) { base[c] = s; pos[c] = s; s += cnt[c]; }
    }
    __syncthreads();
    if (t < 8) { mt[t * 2] = base[t]; mt[t * 2 + 1] = cnt[t]; }
    for (int tok = t; tok < 4800; tok += 256) {
        int c = cls[tok];
        if (c >= 0) { int p = atomicAdd(&pos[c], 1); tl[p] = tok; }
    }
}

// ---------------- weight convert + transpose: Wt[n*K+k] = bf16(W[k*N+n]) ----
__global__ __launch_bounds__(256) void lft_wconv_kernel(
    const float* W0, const float* W1p, const float* W2p, const float* W3p,
    int K, int N, int nTypes, ushort* dst)
{
    int z = blockIdx.z;
    int li = z / nTypes, mi = z % nTypes;
    const float* srcs[4] = {W0, W1p, W2p, W3p};
    const float* src = srcs[mi] + (size_t)li * K * N;
    ushort* outp = dst + (size_t)z * K * N;
    __shared__ float tile[32][33];
    int k0 = blockIdx.x * 32, n0 = blockIdx.y * 32;
    int t = threadIdx.x;
    int r = t >> 3, c4 = (t & 7) << 2;
    float4 v = *(const float4*)&src[(size_t)(k0 + r) * N + n0 + c4];
    tile[r][c4] = v.x; tile[r][c4 + 1] = v.y; tile[r][c4 + 2] = v.z; tile[r][c4 + 3] = v.w;
    __syncthreads();
    ushort4 o;
    o.x = f2b(tile[c4 + 0][r]);
    o.y = f2b(tile[c4 + 1][r]);
    o.z = f2b(tile[c4 + 2][r]);
    o.w = f2b(tile[c4 + 3][r]);
    *(ushort4*)&outp[(size_t)(n0 + r) * K + k0 + c4] = o;
}

// ---------------- bf16 cast of feat0/feat1 (shadows only) ----------------
__global__ __launch_bounds__(256) void lft_cast_kernel(
    const float* __restrict__ f0, const float* __restrict__ f1,
    ushort* fab, ushort* fbb)
{
    long idx = ((long)blockIdx.x * 256 + threadIdx.x) * 4;
    const float* src; ushort* db; long o;
    if (idx < 9830400L) { src = f0; db = fab; o = idx; }
    else                { src = f1; db = fbb; o = idx - 9830400L; }
    float4 v = *(const float4*)&src[o];
    ushort4 u; u.x = f2b(v.x); u.y = f2b(v.y); u.z = f2b(v.z); u.w = f2b(v.w);
    *(ushort4*)&db[o] = u;
}

// ---------------- bf16 MFMA GEMM, 2-phase pipelined: C = act([A0|A1] @ Wt^T) -
__global__ __launch_bounds__(256) void lft_mfma_gemm(
    const ushort* __restrict__ A0, const ushort* __restrict__ A1, int kSplit,
    const ushort* __restrict__ Wt,
    float* Cf, ushort* Cb, int N, int K, int act, int actSplit,
    ushort* Cb2, int N2, int colSplit)
{
    __shared__ ushort As[2][128 * 32];
    __shared__ ushort Bs[2][128 * 32];
    int t = threadIdx.x;
    int nbx = gridDim.x;
    int nwg = nbx * gridDim.y;
    int orig = blockIdx.y * nbx + blockIdx.x;
    int q8 = nwg >> 3;
    int swz = (nwg & 7) ? orig : ((orig & 7) * q8 + (orig >> 3));
    int bx = swz % nbx, by = swz / nbx;
    int m0 = by << 7;
    int n0 = bx << 7;
    int wave = t >> 6, lane = t & 63;
    int wm = wave >> 1, wn = wave & 1;
    int l16 = lane & 15, quad = lane >> 4;
    int r = t >> 2;
    int cu = (t & 3) << 3;
    int fso = (((t & 3) ^ ((r ^ (r >> 2)) & 3)) << 3);
    floatx4 acc[4][4] = {};

    auto stage = [&](int buf, int k0) {
        const ushort* Asrc; int kcol, ldA;
        if (k0 < kSplit) { Asrc = A0; kcol = k0;          ldA = kSplit; }
        else             { Asrc = A1; kcol = k0 - kSplit; ldA = K - kSplit; }
        gload_lds16(&Asrc[(size_t)(m0 + r) * ldA + kcol + fso],      &As[buf][r * 32 + cu]);
        gload_lds16(&Asrc[(size_t)(m0 + r + 64) * ldA + kcol + fso], &As[buf][(r + 64) * 32 + cu]);
        gload_lds16(&Wt[(size_t)(n0 + r) * K + k0 + fso],            &Bs[buf][r * 32 + cu]);
        gload_lds16(&Wt[(size_t)(n0 + r + 64) * K + k0 + fso],       &Bs[buf][(r + 64) * 32 + cu]);
    };

    int qs = ((quad ^ ((l16 ^ (l16 >> 2)) & 3)) << 3);
    stage(0, 0);
    int cur = 0;
    for (int k0 = 0; k0 < K; k0 += 32) {
        if (k0 + 32 < K) {
            stage(cur ^ 1, k0 + 32);
            asm volatile("s_waitcnt vmcnt(4)" ::: "memory");
        } else {
            asm volatile("s_waitcnt vmcnt(0)" ::: "memory");
        }
        __builtin_amdgcn_s_barrier();
        short8 af[4], bfr[4];
#pragma unroll
        for (int i = 0; i < 4; i++) {
            af[i]  = *(const short8*)&As[cur][(wm * 64 + i * 16 + l16) * 32 + qs];
            bfr[i] = *(const short8*)&Bs[cur][(wn * 64 + i * 16 + l16) * 32 + qs];
        }
#pragma unroll
        for (int i = 0; i < 4; i++)
#pragma unroll
            for (int j = 0; j < 4; j++)
                acc[i][j] = __builtin_amdgcn_mfma_f32_16x16x32_bf16(bfr[j], af[i], acc[i][j], 0, 0, 0);
        asm volatile("" ::: "memory");
        __builtin_amdgcn_s_barrier();
        cur ^= 1;
    }
    int effAct = (n0 >= actSplit) ? 0 : act;
    float* Cfp = Cf;
    ushort* Cbp = Cb;
    int ldC = N, cb0 = n0;
    if (Cb2 && n0 >= colSplit) { Cbp = Cb2; Cfp = nullptr; ldC = N2; cb0 = n0 - colSplit; }
#pragma unroll
    for (int i = 0; i < 4; i++) {
        long rowb = m0 + wm * 64 + i * 16 + l16;
#pragma unroll
        for (int j = 0; j < 4; j++) {
            int colb = cb0 + wn * 64 + j * 16 + quad * 4;
            float v0 = acc[i][j][0], v1 = acc[i][j][1], v2 = acc[i][j][2], v3 = acc[i][j][3];
            if (effAct == 1) {
                v0 = v0 > 0.f ? v0 + 1.f : __expf(v0);
                v1 = v1 > 0.f ? v1 + 1.f : __expf(v1);
                v2 = v2 > 0.f ? v2 + 1.f : __expf(v2);
                v3 = v3 > 0.f ? v3 + 1.f : __expf(v3);
            } else if (effAct == 2) {
                v0 = fmaxf(v0, 0.f); v1 = fmaxf(v1, 0.f);
                v2 = fmaxf(v2, 0.f); v3 = fmaxf(v3, 0.f);
            }
            if (Cfp) {
                float4 f4; f4.x = v0; f4.y = v1; f4.z = v2; f4.w = v3;
                *(float4*)&Cfp[rowb * ldC + colb] = f4;
            }
            if (Cbp) {
                ushort4 u4;
                u4.x = f2b(v0); u4.y = f2b(v1); u4.z = f2b(v2); u4.w = f2b(v3);
                *(ushort4*)&Cbp[rowb * ldC + colb] = u4;
            }
        }
    }
}

// ---------------- fused GEMM (N=256 full-row) + LayerNorm epilogue -----------
__global__ __launch_bounds__(256) void lft_gemm_ln(
    const ushort* __restrict__ A, const ushort* __restrict__ Wt, int K,
    const float* __restrict__ g, const float* __restrict__ bb,
    const float* __restrict__ resid, const int* __restrict__ cls,
    float* outF, ushort* __restrict__ outB)
{
    __shared__ ushort As[2][64 * 32];
    __shared__ ushort Bs[2][256 * 32];
    __shared__ float red[4][64][2];
    int t = threadIdx.x;
    long m0 = (long)blockIdx.x << 6;
    int wave = t >> 6, lane = t & 63;
    int wn = wave;
    int l16 = lane & 15, quad = lane >> 4;
    int r = t >> 2;
    int cu = (t & 3) << 3;
    int fso = (((t & 3) ^ ((r ^ (r >> 2)) & 3)) << 3);
    floatx4 acc[4][4] = {};

    auto stage = [&](int buf, int k0) {
        gload_lds16(&A[(m0 + r) * K + k0 + fso], &As[buf][r * 32 + cu]);
#pragma unroll
        for (int s = 0; s < 4; s++)
            gload_lds16(&Wt[(size_t)(s * 64 + r) * K + k0 + fso],
                        &Bs[buf][(s * 64 + r) * 32 + cu]);
    };

    int qs = ((quad ^ ((l16 ^ (l16 >> 2)) & 3)) << 3);
    stage(0, 0);
    int cur = 0;
    for (int k0 = 0; k0 < K; k0 += 32) {
        if (k0 + 32 < K) {
            stage(cur ^ 1, k0 + 32);
            asm volatile("s_waitcnt vmcnt(5)" ::: "memory");
        } else {
            asm volatile("s_waitcnt vmcnt(0)" ::: "memory");
        }
        __builtin_amdgcn_s_barrier();
        short8 af[4], bfr[4];
#pragma unroll
        for (int i = 0; i < 4; i++) {
            af[i]  = *(const short8*)&As[cur][(i * 16 + l16) * 32 + qs];
            bfr[i] = *(const short8*)&Bs[cur][(wn * 64 + i * 16 + l16) * 32 + qs];
        }
#pragma unroll
        for (int i = 0; i < 4; i++)
#pragma unroll
            for (int j = 0; j < 4; j++)
                acc[i][j] = __builtin_amdgcn_mfma_f32_16x16x32_bf16(bfr[j], af[i], acc[i][j], 0, 0, 0);
        asm volatile("" ::: "memory");
        __builtin_amdgcn_s_barrier();
        cur ^= 1;
    }
#pragma unroll
    for (int i = 0; i < 4; i++) {
        float s = 0.f, sq = 0.f;
#pragma unroll
        for (int j = 0; j < 4; j++)
#pragma unroll
            for (int rr = 0; rr < 4; rr++) { float v = acc[i][j][rr]; s += v; sq += v * v; }
        s  += __shfl_xor(s, 16, 64);  sq += __shfl_xor(sq, 16, 64);
        s  += __shfl_xor(s, 32, 64);  sq += __shfl_xor(sq, 32, 64);
        if (quad == 0) {
            int rl = i * 16 + l16;
            red[wn][rl][0] = s;
            red[wn][rl][1] = sq;
        }
    }
    __syncthreads();
#pragma unroll
    for (int i = 0; i < 4; i++) {
        int rl = i * 16 + l16;
        long row = m0 + rl;
        float tsum = red[0][rl][0] + red[1][rl][0] + red[2][rl][0] + red[3][rl][0];
        float tsq  = red[0][rl][1] + red[1][rl][1] + red[2][rl][1] + red[3][rl][1];
        float mean = tsum * (1.0f / 256.0f);
        float var  = tsq * (1.0f / 256.0f) - mean * mean;
        float rsq  = rsqrtf(var + 1e-5f);
        bool keep = true;
        if (cls) keep = (cls[row] >= 0);
#pragma unroll
        for (int j = 0; j < 4; j++) {
            int col = wn * 64 + j * 16 + quad * 4;
            float4 gv = *(const float4*)&g[col];
            float4 bv = *(const float4*)&bb[col];
            float y0 = (acc[i][j][0] - mean) * rsq * gv.x + bv.x;
            float y1 = (acc[i][j][1] - mean) * rsq * gv.y + bv.y;
            float y2 = (acc[i][j][2] - mean) * rsq * gv.z + bv.z;
            float y3 = (acc[i][j][3] - mean) * rsq * gv.w + bv.w;
            if (resid) {
                float4 xr = *(const float4*)&resid[row * 256 + col];
                if (keep) { y0 += xr.x; y1 += xr.y; y2 += xr.z; y3 += xr.w; }
                else      { y0 = xr.x;  y1 = xr.y;  y2 = xr.z;  y3 = xr.w; }
            }
            if (outF) {
                float4 f4; f4.x = y0; f4.y = y1; f4.z = y2; f4.w = y3;
                *(float4*)&outF[row * 256 + col] = f4;
            }
            ushort4 u4;
            u4.x = f2b(y0); u4.y = f2b(y1); u4.z = f2b(y2); u4.w = f2b(y3);
            *(ushort4*)&outB[row * 256 + col] = u4;
        }
    }
}

// ---------------- per-class KV / Ksum reduction, SIDE-MERGED -----------------
// VECTORIZED staging: 32 tokens/step, one 16B short8 load per thread
// (slot=t>>3 token, part=t&7: part<4 -> k quarter, part>=4 -> v quarter),
// padded LDS [32][36] (breaks 128B-stride bank alias; float4 reads stay
// 16B-aligned since (36*j+oe)%4==0). Barriers /4, load width x8.
__global__ __launch_bounds__(256) void lft_kv_kernel(
    const ushort* kvabA, const ushort* kvabB,
    const int* tlA, const int* tlB,
    const int* mtA, const int* mtB, float* kvbase)
{
    int z = blockIdx.z;
    int side = z >> 6, zz = z & 63;
    int chunk = blockIdx.x, c = blockIdx.y;
    int b = zz >> 3, h = zz & 7;
    const ushort* kvab = side ? kvabB : kvabA;
    const int* tlist = side ? tlB : tlA;
    const int* meta  = side ? mtB : mtA;
    float* kv = kvbase + (long)side * KVSTRIDE;
    float* ksum = kv + 524288;
    int off = meta[(b * 8 + c) * 2], n = meta[(b * 8 + c) * 2 + 1];
    int per = (n + KV_NCH - 1) / KV_NCH;
    int s0 = chunk * per;
    int s1 = min(s0 + per, n);
    if (s0 >= s1) return;
    const int* tl = tlist + b * 4800 + off;
    int t = threadIdx.x;
    __shared__ float kb[32][36];
    __shared__ float vb[32][36];
    int od = t >> 3, oe = (t & 7) << 2;
    int slot = t >> 3, part = t & 7, pp = part & 3;
    float a0 = 0.f, a1 = 0.f, a2 = 0.f, a3 = 0.f, ak = 0.f;
    for (int s = s0; s < s1; s += 32) {
        __syncthreads();   // previous step's LDS reads complete
        float* dstl = (part >= 4) ? &vb[slot][pp * 8] : &kb[slot][pp * 8];
        if (s + slot < s1) {
            int tok = tl[s + slot];
            long bse = ((long)b * 4800 + tok) * 512 + h * 32
                     + (part >= 4 ? 256 : 0) + pp * 8;
            short8 v8 = *(const short8*)&kvab[bse];
#pragma unroll
            for (int q = 0; q < 8; q++) dstl[q] = b2f((ushort)v8[q]);
        } else {
#pragma unroll
            for (int q = 0; q < 8; q++) dstl[q] = 0.f;
        }
        __syncthreads();
        int jmax = min(32, s1 - s);
        for (int j = 0; j < jmax; j++) {
            float kd = kb[j][od];
            float4 vv = *(const float4*)&vb[j][oe];
            a0 += kd * vv.x; a1 += kd * vv.y; a2 += kd * vv.z; a3 += kd * vv.w;
            ak += kd;
        }
    }
    float* dst = kv + (((long)(b * NPROTO + c) * 8 + h) << 10) + od * 32 + oe;
    atomicAdd(dst + 0, a0);
    atomicAdd(dst + 1, a1);
    atomicAdd(dst + 2, a2);
    atomicAdd(dst + 3, a3);
    if ((t & 7) == 0)
        atomicAdd(ksum + (((long)(b * NPROTO + c) * 8 + h) << 5) + od, ak);
}

// ---------------- kv fp32 -> bf16 B-layout, SIDE-MERGED ----------------------
__global__ __launch_bounds__(256) void lft_kvconv_kernel(
    const float* kvbase, ushort* kvtA, ushort* kvtB)
{
    int idx = blockIdx.x;
    int side = idx >> 6, bc = idx & 63;
    const float* kvb = kvbase + (long)side * KVSTRIDE;
    const float* ksb = kvb + 524288;
    ushort* kvt = side ? kvtB : kvtA;
    int t = threadIdx.x;
    int h = t >> 5, d = t & 31;
    const float* kvsrc = kvb + ((long)bc * 8 + h) * 1024;
    const float* kssrc = ksb + ((long)bc * 8 + h) * 32;
    ushort* dst = kvt + ((long)bc * 8 + h) * 1536;
#pragma unroll
    for (int e = 0; e < 32; e++) dst[e * 32 + d] = f2b(kvsrc[d * 32 + e]);
    dst[32 * 32 + d] = f2b(kssrc[d]);
#pragma unroll
    for (int e = 33; e < 48; e++) dst[e * 32 + d] = 0;
}

// ---------------- msg via MFMA, SIDE-MERGED ----------------------------------
__global__ __launch_bounds__(256) void lft_msg_kernel(
    const ushort* qA, const ushort* qB,
    const ushort* kvtA, const ushort* kvtB,
    const int* tlA, const int* tlB, const int* mtA, const int* mtB,
    ushort* msgA_, ushort* msgB_)
{
    int z = blockIdx.z;
    int side = z >> 3, b = z & 7;
    int chunk = blockIdx.x, c = blockIdx.y;
    const ushort* pq = side ? qB : qA;
    const ushort* kvt = side ? kvtB : kvtA;
    const int* tlist = side ? tlB : tlA;
    const int* meta  = side ? mtB : mtA;
    ushort* msg = side ? msgB_ : msgA_;
    int off = meta[(b * 8 + c) * 2], n = meta[(b * 8 + c) * 2 + 1];
    int per = (n + MSG_NCH - 1) / MSG_NCH;
    int s0 = chunk * per, s1 = min(s0 + per, n);
    if (s0 >= s1) return;
    const int* tl = tlist + b * 4800 + off;
    int t = threadIdx.x;
    int wave = t >> 6, lane = t & 63;
    int l16 = lane & 15, quad = lane >> 4;
    int bc = b * 8 + c;
    short8 bfr[2][3];
#pragma unroll
    for (int hh = 0; hh < 2; hh++) {
        int h = wave * 2 + hh;
        const ushort* kb = kvt + ((long)bc * 8 + h) * 1536;
#pragma unroll
        for (int nt = 0; nt < 3; nt++)
            bfr[hh][nt] = *(const short8*)&kb[(nt * 16 + l16) * 32 + quad * 8];
    }
    for (int s = s0; s < s1; s += 16) {
        int ia = min(s + l16, s1 - 1);
        int tokA = tl[ia];
        long rowA = (long)b * 4800 + tokA;
#pragma unroll
        for (int hh = 0; hh < 2; hh++) {
            int h = wave * 2 + hh;
            short8 a = *(const short8*)&pq[rowA * 256 + h * 32 + quad * 8];
            floatx4 n0 = {}, n1 = {}, dd = {};
            n0 = __builtin_amdgcn_mfma_f32_16x16x32_bf16(a, bfr[hh][0], n0, 0, 0, 0);
            n1 = __builtin_amdgcn_mfma_f32_16x16x32_bf16(a, bfr[hh][1], n1, 0, 0, 0);
            dd = __builtin_amdgcn_mfma_f32_16x16x32_bf16(a, bfr[hh][2], dd, 0, 0, 0);
#pragma unroll
            for (int r = 0; r < 4; r++) {
                int rowi = s + quad * 4 + r;
                float den = __shfl(dd[r], lane & 48, 64);
                float inv = 1.f / (den + 1e-6f);
                int tokr = __shfl(tokA, quad * 4 + r, 64);
                if (rowi < s1) {
                    long base = ((long)b * 4800 + tokr) * 256 + h * 32;
                    msg[base + l16]      = f2b(n0[r] * inv);
                    msg[base + 16 + l16] = f2b(n1[r] * inv);
                }
            }
        }
    }
}

extern "C" void kernel_launch(void* const* d_in, const int* in_sizes, int n_in,
                              void* d_out, int out_size, void* d_ws, size_t ws_size,
                              hipStream_t stream)
{
    (void)in_sizes; (void)n_in; (void)out_size; (void)ws_size;
    const float* feat0 = (const float*)d_in[0];
    const float* feat1 = (const float*)d_in[1];
    const int*   mask0 = (const int*)d_in[2];
    const int*   mask1 = (const int*)d_in[3];
    const float* f0wo  = (const float*)d_in[4];
    const float* f1wo  = (const float*)d_in[5];
    const float* proto = (const float*)d_in[6];
    const float* Wq = (const float*)d_in[7];
    const float* Wk = (const float*)d_in[8];
    const float* Wv = (const float*)d_in[9];
    const float* Wm = (const float*)d_in[10];
    const float* W1 = (const float*)d_in[11];
    const float* W2 = (const float*)d_in[12];
    const float* g1 = (const float*)d_in[13];
    const float* b1 = (const float*)d_in[14];
    const float* g2 = (const float*)d_in[15];
    const float* b2 = (const float*)d_in[16];
    float* out = (float*)d_out;
    float* ws = (float*)d_ws;

    // ---- workspace layout ----
    const long FSZ = 9830400L;               // 8*4800*256
    float* fa = ws;                          // fp32 master feat0
    float* fb = ws + FSZ;                    // fp32 master feat1
    ushort* kvab0 = (ushort*)(ws + 2 * FSZ);
    ushort* kvab1 = (ushort*)(ws + 3 * FSZ);
    ushort* msgA  = (ushort*)(ws + 2 * FSZ);        // first half of R2
    ushort* msgB  = (ushort*)(ws + 2 * FSZ) + FSZ;  // second half of R2
    ushort* hidA  = (ushort*)(ws + 3 * FSZ);        // all of R3
    ushort* kvt1  = (ushort*)(ws + 3 * FSZ);        // evens: over dead kvab1
    ushort* ub  = (ushort*)(ws + 4 * FSZ);
    ushort* fa_bf = ub;
    ushort* fb_bf = ub + FSZ;
    ushort* qb1   = ub + 2 * FSZ;
    ushort* qb0   = ub + 3 * FSZ;
    ushort* wb    = ub + 4 * FSZ;
    ushort* wb1   = wb + 16 * 65536;
    ushort* wb2   = wb1 + 4 * 262144;
    ushort* kvt0  = wb2 + 4 * 131072;
    float* kvb = (float*)(kvt0 + 786432);
    int* cls0 = (int*)(kvb + 2 * KVSTRIDE);
    int* cls1 = cls0 + 38400;
    int* tl0  = cls1 + 38400;
    int* tl1  = tl0 + 38400;
    int* meta = tl1 + 38400;

    // one-time per launch
    lft_wconv_kernel<<<dim3(8, 8, 16), 256, 0, stream>>>(Wq, Wk, Wv, Wm, 256, 256, 4, wb);
    lft_wconv_kernel<<<dim3(16, 16, 4), 256, 0, stream>>>(W1, W1, W1, W1, 512, 512, 1, wb1);
    lft_wconv_kernel<<<dim3(16, 8, 4), 256, 0, stream>>>(W2, W2, W2, W2, 512, 256, 1, wb2);
    lft_cast_kernel<<<19200, 256, 0, stream>>>(feat0, feat1, fa_bf, fb_bf);
    hipMemcpyAsync(out + 20352000L, proto, 2048 * 4, hipMemcpyDeviceToDevice, stream);
    lft_class_kernel<<<19200, 256, 0, stream>>>(f0wo, f1wo, mask0, mask1, proto,
                                                out, cls0, cls1);
    lft_sort_kernel<<<16, 256, 0, stream>>>(cls0, cls1, tl0, tl1, meta);

    for (int li = 0; li < 4; li++) {
        const ushort* wq = wb + (size_t)(li * 4 + 0) * 65536;
        const ushort* wk = wb + (size_t)(li * 4 + 1) * 65536;
        const ushort* wm = wb + (size_t)(li * 4 + 3) * 65536;
        const ushort* w1 = wb1 + (size_t)li * 262144;
        const ushort* w2 = wb2 + (size_t)li * 131072;
        const float* g1p = g1 + li * 256; const float* b1p = b1 + li * 256;
        const float* g2p = g2 + li * 256; const float* b2p = b2 + li * 256;
        dim3 blk(256);
        dim3 gA(2, 300), gB(4, 300), gQ(6, 300);

        const float* ra = (li == 0) ? feat0 : fa;
        const float* rb = (li == 0) ? feat1 : fb;
        float* oa = (li == 3) ? out : fa;
        float* ob = (li == 3) ? (out + FSZ) : fb;

        if ((li & 1) == 0) {
            // ===== self-self: merged phase1 (both sides), then phase2 x2 =====
            lft_mfma_gemm<<<gQ, blk, 0, stream>>>(fa_bf, fa_bf, 256, wq,
                nullptr, qb0, 256, 256, 1, 512, kvab0, 512, 256);
            lft_mfma_gemm<<<gQ, blk, 0, stream>>>(fb_bf, fb_bf, 256, wq,
                nullptr, qb1, 256, 256, 1, 512, kvab1, 512, 256);
            hipMemsetAsync(kvb, 0, 2 * KVSTRIDE * 4, stream);
            lft_kv_kernel<<<dim3(KV_NCH, 8, 128), blk, 0, stream>>>(
                kvab0, kvab1, tl0, tl1, meta, meta + 128, kvb);
            lft_kvconv_kernel<<<128, blk, 0, stream>>>(kvb, kvt0, kvt1);
            lft_msg_kernel<<<dim3(MSG_NCH, 8, 16), blk, 0, stream>>>(
                qb0, qb1, kvt0, kvt1, tl0, tl1, meta, meta + 128, msgA, msgB);
            lft_gemm_ln<<<600, blk, 0, stream>>>(msgA, wm, 256, g1p, b1p,
                                                 nullptr, nullptr, nullptr, msgA);
            lft_mfma_gemm<<<gB, blk, 0, stream>>>(fa_bf, msgA, 256, w1,
                nullptr, hidA, 512, 512, 2, 512, nullptr, 0, 0);
            lft_gemm_ln<<<600, blk, 0, stream>>>(hidA, w2, 512, g2p, b2p,
                                                 ra, cls0, oa, fa_bf);
            lft_gemm_ln<<<600, blk, 0, stream>>>(msgB, wm, 256, g1p, b1p,
                                                 nullptr, nullptr, nullptr, msgB);
            lft_mfma_gemm<<<gB, blk, 0, stream>>>(fb_bf, msgB, 256, w1,
                nullptr, hidA, 512, 512, 2, 512, nullptr, 0, 0);
            lft_gemm_ln<<<600, blk, 0, stream>>>(hidA, w2, 512, g2p, b2p,
                                                 rb, cls1, ob, fb_bf);
        } else {
            // ===== cross-self: sequential sides =====
            lft_mfma_gemm<<<gA, blk, 0, stream>>>(fa_bf, fa_bf, 256, wq,
                nullptr, qb0, 256, 256, 1, 256, nullptr, 0, 0);
            lft_mfma_gemm<<<gB, blk, 0, stream>>>(fb_bf, fb_bf, 256, wk,
                nullptr, kvab0, 512, 256, 1, 256, nullptr, 0, 0);
            hipMemsetAsync(kvb, 0, KVSTRIDE * 4, stream);
            lft_kv_kernel<<<dim3(KV_NCH, 8, 64), blk, 0, stream>>>(
                kvab0, nullptr, tl1, nullptr, meta + 128, nullptr, kvb);
            lft_kvconv_kernel<<<64, blk, 0, stream>>>(kvb, kvt0, nullptr);
            lft_msg_kernel<<<dim3(MSG_NCH, 8, 8), blk, 0, stream>>>(
                qb0, nullptr, kvt0, nullptr, tl0, nullptr, meta, nullptr, msgA, nullptr);
            lft_gemm_ln<<<600, blk, 0, stream>>>(msgA, wm, 256, g1p, b1p,
                                                 nullptr, nullptr, nullptr, msgA);
            lft_mfma_gemm<<<gB, blk, 0, stream>>>(fa_bf, msgA, 256, w1,
                nullptr, hidA, 512, 512, 2, 512, nullptr, 0, 0);
            lft_gemm_ln<<<600, blk, 0, stream>>>(hidA, w2, 512, g2p, b2p,
                                                 ra, cls0, oa, fa_bf);
            lft_mfma_gemm<<<gA, blk, 0, stream>>>(fb_bf, fb_bf, 256, wq,
                nullptr, qb0, 256, 256, 1, 256, nullptr, 0, 0);
            lft_mfma_gemm<<<gB, blk, 0, stream>>>(fa_bf, fa_bf, 256, wk,
                nullptr, kvab0, 512, 256, 1, 256, nullptr, 0, 0);
            hipMemsetAsync(kvb, 0, KVSTRIDE * 4, stream);
            lft_kv_kernel<<<dim3(KV_NCH, 8, 64), blk, 0, stream>>>(
                kvab0, nullptr, tl0, nullptr, meta, nullptr, kvb);
            lft_kvconv_kernel<<<64, blk, 0, stream>>>(kvb, kvt0, nullptr);
            lft_msg_kernel<<<dim3(MSG_NCH, 8, 8), blk, 0, stream>>>(
                qb0, nullptr, kvt0, nullptr, tl1, nullptr, meta + 128, nullptr, msgA, nullptr);
            lft_gemm_ln<<<600, blk, 0, stream>>>(msgA, wm, 256, g1p, b1p,
                                                 nullptr, nullptr, nullptr, msgA);
            lft_mfma_gemm<<<gB, blk, 0, stream>>>(fb_bf, msgA, 256, w1,
                nullptr, hidA, 512, 512, 2, 512, nullptr, 0, 0);
            lft_gemm_ln<<<600, blk, 0, stream>>>(hidA, w2, 512, g2p, b2p,
                                                 rb, cls1, ob, fb_bf);
        }
    }
}

// Round 18
// 1387.014 us; speedup vs baseline: 1.1499x; 1.1142x over previous
//
#include <hip/hip_runtime.h>
#include <math.h>

#define NPROTO 8
#define MSG_NCH 8
#define KVSTRIDE 540672L   // per-side kv scratch: 524288 (kv) + 16384 (ksum) floats

typedef __attribute__((ext_vector_type(8))) short short8;
typedef __attribute__((ext_vector_type(4))) float floatx4;

static __device__ __forceinline__ ushort f2b(float f) {
    unsigned u = __builtin_bit_cast(unsigned, f);
    unsigned r = (u + 0x7fffu + ((u >> 16) & 1u)) >> 16;
    return (ushort)r;
}

static __device__ __forceinline__ float b2f(ushort u) {
    return __builtin_bit_cast(float, ((unsigned)u) << 16);
}

typedef __attribute__((address_space(1))) void gvoid;
typedef __attribute__((address_space(3))) void lvoid;

static __device__ __forceinline__ void gload_lds16(const ushort* g, ushort* l) {
    __builtin_amdgcn_global_load_lds((gvoid*)(void*)g, (lvoid*)l, 16, 0, 0);
}

// ---------------- prototype projection / argmax-class kernel ----------------
__global__ __launch_bounds__(256) void lft_class_kernel(
    const float* __restrict__ f0wo, const float* __restrict__ f1wo,
    const int* __restrict__ mask0, const int* __restrict__ mask1,
    const float* __restrict__ proto,
    float* out, int* cls0, int* cls1)
{
    __shared__ float pr[2048];
    int t = threadIdx.x;
    *(float4*)&pr[t * 4]        = *(const float4*)&proto[t * 4];
    *(float4*)&pr[1024 + t * 4] = *(const float4*)&proto[1024 + t * 4];
    __syncthreads();
    int wave = t >> 6, lane = t & 63;
    long token = (long)blockIdx.x * 4 + wave;
    const float* fsrc; const int* msrc; float* fpout; float* clsout; int* clsarr; long tok;
    if (token < 38400) {
        tok = token; fsrc = f0wo; msrc = mask0;
        fpout = out + 19737600L; clsout = out + 19660800L; clsarr = cls0;
    } else {
        tok = token - 38400; fsrc = f1wo; msrc = mask1;
        fpout = out + 20044800L; clsout = out + 19699200L; clsarr = cls1;
    }
    float4 f = *(const float4*)&fsrc[tok * 256 + lane * 4];
    float s[NPROTO];
#pragma unroll
    for (int p = 0; p < NPROTO; p++) {
        float4 pv = *(const float4*)&pr[p * 256 + lane * 4];
        s[p] = f.x * pv.x + f.y * pv.y + f.z * pv.z + f.w * pv.w;
    }
    float k0_ = (lane & 1) ? s[4] : s[0], d0 = (lane & 1) ? s[0] : s[4];
    float k1_ = (lane & 1) ? s[5] : s[1], d1 = (lane & 1) ? s[1] : s[5];
    float k2_ = (lane & 1) ? s[6] : s[2], d2 = (lane & 1) ? s[2] : s[6];
    float k3_ = (lane & 1) ? s[7] : s[3], d3 = (lane & 1) ? s[3] : s[7];
    float w0 = k0_ + __shfl_xor(d0, 1, 64);
    float w1 = k1_ + __shfl_xor(d1, 1, 64);
    float w2 = k2_ + __shfl_xor(d2, 1, 64);
    float w3 = k3_ + __shfl_xor(d3, 1, 64);
    float u0k = (lane & 2) ? w2 : w0, u0d = (lane & 2) ? w0 : w2;
    float u1k = (lane & 2) ? w3 : w1, u1d = (lane & 2) ? w1 : w3;
    float x0 = u0k + __shfl_xor(u0d, 2, 64);
    float x1 = u1k + __shfl_xor(u1d, 2, 64);
    float yk = (lane & 4) ? x1 : x0, yd = (lane & 4) ? x0 : x1;
    float sc = yk + __shfl_xor(yd, 4, 64);
    sc += __shfl_xor(sc, 8, 64);
    sc += __shfl_xor(sc, 16, 64);
    sc += __shfl_xor(sc, 32, 64);
    int p = ((lane & 1) << 2) | (lane & 2) | ((lane >> 2) & 1);
    if (lane < 8) fpout[tok * 8 + p] = sc;
    float bv = sc; int bi = p;
#pragma unroll
    for (int o = 1; o < 8; o <<= 1) {
        float ov = __shfl_xor(bv, o, 64);
        int oi = __shfl_xor(bi, o, 64);
        if (ov > bv || (ov == bv && oi < bi)) { bv = ov; bi = oi; }
    }
    if (lane == 0) {
        clsout[tok] = (float)bi;
        clsarr[tok] = msrc[tok] ? bi : -1;
    }
}

// ---------------- counting sort of tokens by (batch,class) -------------------
__global__ __launch_bounds__(256) void lft_sort_kernel(
    const int* __restrict__ cls0, const int* __restrict__ cls1,
    int* tl0, int* tl1, int* meta)
{
    int g = blockIdx.x; int L = g >> 3, b = g & 7;
    const int* cls = (L ? cls1 : cls0) + b * 4800;
    int* tl = (L ? tl1 : tl0) + b * 4800;
    int* mt = meta + (L * 8 + b) * 16;
    __shared__ int cnt[8], base[8], pos[8];
    int t = threadIdx.x;
    if (t < 8) cnt[t] = 0;
    __syncthreads();
    for (int tok = t; tok < 4800; tok += 256) {
        int c = cls[tok];
        if (c >= 0) atomicAdd(&cnt[c], 1);
    }
    __syncthreads();
    if (t == 0) {
        int s = 0;
        for (int c = 0; c < 8; c++) { base[c] = s; pos[c] = s; s += cnt[c]; }
    }
    __syncthreads();
    if (t < 8) { mt[t * 2] = base[t]; mt[t * 2 + 1] = cnt[t]; }
    for (int tok = t; tok < 4800; tok += 256) {
        int c = cls[tok];
        if (c >= 0) { int p = atomicAdd(&pos[c], 1); tl[p] = tok; }
    }
}

// ---------------- weight convert + transpose: Wt[n*K+k] = bf16(W[k*N+n]) ----
__global__ __launch_bounds__(256) void lft_wconv_kernel(
    const float* W0, const float* W1p, const float* W2p, const float* W3p,
    int K, int N, int nTypes, ushort* dst)
{
    int z = blockIdx.z;
    int li = z / nTypes, mi = z % nTypes;
    const float* srcs[4] = {W0, W1p, W2p, W3p};
    const float* src = srcs[mi] + (size_t)li * K * N;
    ushort* outp = dst + (size_t)z * K * N;
    __shared__ float tile[32][33];
    int k0 = blockIdx.x * 32, n0 = blockIdx.y * 32;
    int t = threadIdx.x;
    int r = t >> 3, c4 = (t & 7) << 2;
    float4 v = *(const float4*)&src[(size_t)(k0 + r) * N + n0 + c4];
    tile[r][c4] = v.x; tile[r][c4 + 1] = v.y; tile[r][c4 + 2] = v.z; tile[r][c4 + 3] = v.w;
    __syncthreads();
    ushort4 o;
    o.x = f2b(tile[c4 + 0][r]);
    o.y = f2b(tile[c4 + 1][r]);
    o.z = f2b(tile[c4 + 2][r]);
    o.w = f2b(tile[c4 + 3][r]);
    *(ushort4*)&outp[(size_t)(n0 + r) * K + k0 + c4] = o;
}

// ---------------- bf16 cast of feat0/feat1 (shadows only) ----------------
__global__ __launch_bounds__(256) void lft_cast_kernel(
    const float* __restrict__ f0, const float* __restrict__ f1,
    ushort* fab, ushort* fbb)
{
    long idx = ((long)blockIdx.x * 256 + threadIdx.x) * 4;
    const float* src; ushort* db; long o;
    if (idx < 9830400L) { src = f0; db = fab; o = idx; }
    else                { src = f1; db = fbb; o = idx - 9830400L; }
    float4 v = *(const float4*)&src[o];
    ushort4 u; u.x = f2b(v.x); u.y = f2b(v.y); u.z = f2b(v.z); u.w = f2b(v.w);
    *(ushort4*)&db[o] = u;
}

// ---------------- bf16 MFMA GEMM, 2-phase pipelined: C = act([A0|A1] @ Wt^T) -
__global__ __launch_bounds__(256) void lft_mfma_gemm(
    const ushort* __restrict__ A0, const ushort* __restrict__ A1, int kSplit,
    const ushort* __restrict__ Wt,
    float* Cf, ushort* Cb, int N, int K, int act, int actSplit,
    ushort* Cb2, int N2, int colSplit)
{
    __shared__ ushort As[2][128 * 32];
    __shared__ ushort Bs[2][128 * 32];
    int t = threadIdx.x;
    int nbx = gridDim.x;
    int nwg = nbx * gridDim.y;
    int orig = blockIdx.y * nbx + blockIdx.x;
    int q8 = nwg >> 3;
    int swz = (nwg & 7) ? orig : ((orig & 7) * q8 + (orig >> 3));
    int bx = swz % nbx, by = swz / nbx;
    int m0 = by << 7;
    int n0 = bx << 7;
    int wave = t >> 6, lane = t & 63;
    int wm = wave >> 1, wn = wave & 1;
    int l16 = lane & 15, quad = lane >> 4;
    int r = t >> 2;
    int cu = (t & 3) << 3;
    int fso = (((t & 3) ^ ((r ^ (r >> 2)) & 3)) << 3);
    floatx4 acc[4][4] = {};

    auto stage = [&](int buf, int k0) {
        const ushort* Asrc; int kcol, ldA;
        if (k0 < kSplit) { Asrc = A0; kcol = k0;          ldA = kSplit; }
        else             { Asrc = A1; kcol = k0 - kSplit; ldA = K - kSplit; }
        gload_lds16(&Asrc[(size_t)(m0 + r) * ldA + kcol + fso],      &As[buf][r * 32 + cu]);
        gload_lds16(&Asrc[(size_t)(m0 + r + 64) * ldA + kcol + fso], &As[buf][(r + 64) * 32 + cu]);
        gload_lds16(&Wt[(size_t)(n0 + r) * K + k0 + fso],            &Bs[buf][r * 32 + cu]);
        gload_lds16(&Wt[(size_t)(n0 + r + 64) * K + k0 + fso],       &Bs[buf][(r + 64) * 32 + cu]);
    };

    int qs = ((quad ^ ((l16 ^ (l16 >> 2)) & 3)) << 3);
    stage(0, 0);
    int cur = 0;
    for (int k0 = 0; k0 < K; k0 += 32) {
        if (k0 + 32 < K) {
            stage(cur ^ 1, k0 + 32);
            asm volatile("s_waitcnt vmcnt(4)" ::: "memory");
        } else {
            asm volatile("s_waitcnt vmcnt(0)" ::: "memory");
        }
        __builtin_amdgcn_s_barrier();
        short8 af[4], bfr[4];
#pragma unroll
        for (int i = 0; i < 4; i++) {
            af[i]  = *(const short8*)&As[cur][(wm * 64 + i * 16 + l16) * 32 + qs];
            bfr[i] = *(const short8*)&Bs[cur][(wn * 64 + i * 16 + l16) * 32 + qs];
        }
#pragma unroll
        for (int i = 0; i < 4; i++)
#pragma unroll
            for (int j = 0; j < 4; j++)
                acc[i][j] = __builtin_amdgcn_mfma_f32_16x16x32_bf16(bfr[j], af[i], acc[i][j], 0, 0, 0);
        asm volatile("" ::: "memory");
        __builtin_amdgcn_s_barrier();
        cur ^= 1;
    }
    int effAct = (n0 >= actSplit) ? 0 : act;
    float* Cfp = Cf;
    ushort* Cbp = Cb;
    int ldC = N, cb0 = n0;
    if (Cb2 && n0 >= colSplit) { Cbp = Cb2; Cfp = nullptr; ldC = N2; cb0 = n0 - colSplit; }
#pragma unroll
    for (int i = 0; i < 4; i++) {
        long rowb = m0 + wm * 64 + i * 16 + l16;
#pragma unroll
        for (int j = 0; j < 4; j++) {
            int colb = cb0 + wn * 64 + j * 16 + quad * 4;
            float v0 = acc[i][j][0], v1 = acc[i][j][1], v2 = acc[i][j][2], v3 = acc[i][j][3];
            if (effAct == 1) {
                v0 = v0 > 0.f ? v0 + 1.f : __expf(v0);
                v1 = v1 > 0.f ? v1 + 1.f : __expf(v1);
                v2 = v2 > 0.f ? v2 + 1.f : __expf(v2);
                v3 = v3 > 0.f ? v3 + 1.f : __expf(v3);
            } else if (effAct == 2) {
                v0 = fmaxf(v0, 0.f); v1 = fmaxf(v1, 0.f);
                v2 = fmaxf(v2, 0.f); v3 = fmaxf(v3, 0.f);
            }
            if (Cfp) {
                float4 f4; f4.x = v0; f4.y = v1; f4.z = v2; f4.w = v3;
                *(float4*)&Cfp[rowb * ldC + colb] = f4;
            }
            if (Cbp) {
                ushort4 u4;
                u4.x = f2b(v0); u4.y = f2b(v1); u4.z = f2b(v2); u4.w = f2b(v3);
                *(ushort4*)&Cbp[rowb * ldC + colb] = u4;
            }
        }
    }
}

// ---------------- fused GEMM (N=256 full-row) + LayerNorm epilogue -----------
__global__ __launch_bounds__(256) void lft_gemm_ln(
    const ushort* __restrict__ A, const ushort* __restrict__ Wt, int K,
    const float* __restrict__ g, const float* __restrict__ bb,
    const float* __restrict__ resid, const int* __restrict__ cls,
    float* outF, ushort* __restrict__ outB)
{
    __shared__ ushort As[2][64 * 32];
    __shared__ ushort Bs[2][256 * 32];
    __shared__ float red[4][64][2];
    int t = threadIdx.x;
    long m0 = (long)blockIdx.x << 6;
    int wave = t >> 6, lane = t & 63;
    int wn = wave;
    int l16 = lane & 15, quad = lane >> 4;
    int r = t >> 2;
    int cu = (t & 3) << 3;
    int fso = (((t & 3) ^ ((r ^ (r >> 2)) & 3)) << 3);
    floatx4 acc[4][4] = {};

    auto stage = [&](int buf, int k0) {
        gload_lds16(&A[(m0 + r) * K + k0 + fso], &As[buf][r * 32 + cu]);
#pragma unroll
        for (int s = 0; s < 4; s++)
            gload_lds16(&Wt[(size_t)(s * 64 + r) * K + k0 + fso],
                        &Bs[buf][(s * 64 + r) * 32 + cu]);
    };

    int qs = ((quad ^ ((l16 ^ (l16 >> 2)) & 3)) << 3);
    stage(0, 0);
    int cur = 0;
    for (int k0 = 0; k0 < K; k0 += 32) {
        if (k0 + 32 < K) {
            stage(cur ^ 1, k0 + 32);
            asm volatile("s_waitcnt vmcnt(5)" ::: "memory");
        } else {
            asm volatile("s_waitcnt vmcnt(0)" ::: "memory");
        }
        __builtin_amdgcn_s_barrier();
        short8 af[4], bfr[4];
#pragma unroll
        for (int i = 0; i < 4; i++) {
            af[i]  = *(const short8*)&As[cur][(i * 16 + l16) * 32 + qs];
            bfr[i] = *(const short8*)&Bs[cur][(wn * 64 + i * 16 + l16) * 32 + qs];
        }
#pragma unroll
        for (int i = 0; i < 4; i++)
#pragma unroll
            for (int j = 0; j < 4; j++)
                acc[i][j] = __builtin_amdgcn_mfma_f32_16x16x32_bf16(bfr[j], af[i], acc[i][j], 0, 0, 0);
        asm volatile("" ::: "memory");
        __builtin_amdgcn_s_barrier();
        cur ^= 1;
    }
#pragma unroll
    for (int i = 0; i < 4; i++) {
        float s = 0.f, sq = 0.f;
#pragma unroll
        for (int j = 0; j < 4; j++)
#pragma unroll
            for (int rr = 0; rr < 4; rr++) { float v = acc[i][j][rr]; s += v; sq += v * v; }
        s  += __shfl_xor(s, 16, 64);  sq += __shfl_xor(sq, 16, 64);
        s  += __shfl_xor(s, 32, 64);  sq += __shfl_xor(sq, 32, 64);
        if (quad == 0) {
            int rl = i * 16 + l16;
            red[wn][rl][0] = s;
            red[wn][rl][1] = sq;
        }
    }
    __syncthreads();
#pragma unroll
    for (int i = 0; i < 4; i++) {
        int rl = i * 16 + l16;
        long row = m0 + rl;
        float tsum = red[0][rl][0] + red[1][rl][0] + red[2][rl][0] + red[3][rl][0];
        float tsq  = red[0][rl][1] + red[1][rl][1] + red[2][rl][1] + red[3][rl][1];
        float mean = tsum * (1.0f / 256.0f);
        float var  = tsq * (1.0f / 256.0f) - mean * mean;
        float rsq  = rsqrtf(var + 1e-5f);
        bool keep = true;
        if (cls) keep = (cls[row] >= 0);
#pragma unroll
        for (int j = 0; j < 4; j++) {
            int col = wn * 64 + j * 16 + quad * 4;
            float4 gv = *(const float4*)&g[col];
            float4 bv = *(const float4*)&bb[col];
            float y0 = (acc[i][j][0] - mean) * rsq * gv.x + bv.x;
            float y1 = (acc[i][j][1] - mean) * rsq * gv.y + bv.y;
            float y2 = (acc[i][j][2] - mean) * rsq * gv.z + bv.z;
            float y3 = (acc[i][j][3] - mean) * rsq * gv.w + bv.w;
            if (resid) {
                float4 xr = *(const float4*)&resid[row * 256 + col];
                if (keep) { y0 += xr.x; y1 += xr.y; y2 += xr.z; y3 += xr.w; }
                else      { y0 = xr.x;  y1 = xr.y;  y2 = xr.z;  y3 = xr.w; }
            }
            if (outF) {
                float4 f4; f4.x = y0; f4.y = y1; f4.z = y2; f4.w = y3;
                *(float4*)&outF[row * 256 + col] = f4;
            }
            ushort4 u4;
            u4.x = f2b(y0); u4.y = f2b(y1); u4.z = f2b(y2); u4.w = f2b(y3);
            *(ushort4*)&outB[row * 256 + col] = u4;
        }
    }
}

// ---------------- per-class KV via MFMA: kv = K^T V, ksum = K^T 1 ------------
// One block OWNS (side,b,c,h): no chunks, no atomics, no memset needed.
// Per step: stage 128 tokens TRANSPOSED bf16 (kbT[d][s], vbT[e][s], slice-
// padded stride 1288); wave w consumes slice w with 4x mfma_16x16x32_bf16
// (A=K^T rows d, B=V^T rows e -> D[d=quad*4+r][e=l16]). ksum from A-frags.
// Block-internal wave-phased LDS reduction -> coalesced float4 stores.
__global__ __launch_bounds__(256) void lft_kv_kernel(
    const ushort* kvabA, const ushort* kvabB,
    const int* tlA, const int* tlB,
    const int* mtA, const int* mtB, float* kvbase)
{
    int h = blockIdx.x, c = blockIdx.y;
    int z = blockIdx.z;
    int side = z >> 3, b = z & 7;
    const ushort* kvab = side ? kvabB : kvabA;
    const int* tlist = side ? tlB : tlA;
    const int* meta  = side ? mtB : mtA;
    float* kv = kvbase + (long)side * KVSTRIDE;
    float* ksum = kv + 524288;
    int off = meta[(b * 8 + c) * 2], n = meta[(b * 8 + c) * 2 + 1];
    const int* tl = tlist + b * 4800 + off;
    int t = threadIdx.x;
    int wave = t >> 6, lane = t & 63;
    int l16 = lane & 15, quad = lane >> 4;
    __shared__ ushort kbT[4 * 1288];   // [slice][d*40 + s], bf16
    __shared__ ushort vbT[4 * 1288];
    int sl = t & 127, half = t >> 7;
    int slice = sl >> 5, s32 = sl & 31;
    ushort* dstT = (half ? vbT : kbT) + slice * 1288 + s32;
    floatx4 acc00 = {}, acc01 = {}, acc10 = {}, acc11 = {};
    float ksr0 = 0.f, ksr1 = 0.f;
    long bch = (long)(b * NPROTO + c) * 8 + h;
    for (int s = 0; s < n; s += 128) {
        __syncthreads();   // prior step's fragment reads complete
        int si = s + sl;
        if (si < n) {
            int tok = tl[si];
            const ushort* src = kvab + ((long)b * 4800 + tok) * 512 + h * 32 + half * 256;
#pragma unroll
            for (int j = 0; j < 4; j++) {
                short8 v8 = *(const short8*)&src[j * 8];
#pragma unroll
                for (int q = 0; q < 8; q++) dstT[(j * 8 + q) * 40] = (ushort)v8[q];
            }
        } else {
#pragma unroll
            for (int d = 0; d < 32; d++) dstT[d * 40] = 0;
        }
        __syncthreads();
        const ushort* kt = kbT + wave * 1288;
        const ushort* vt = vbT + wave * 1288;
        short8 ka0 = *(const short8*)&kt[l16 * 40 + quad * 8];
        short8 ka1 = *(const short8*)&kt[(16 + l16) * 40 + quad * 8];
        short8 va0 = *(const short8*)&vt[l16 * 40 + quad * 8];
        short8 va1 = *(const short8*)&vt[(16 + l16) * 40 + quad * 8];
        acc00 = __builtin_amdgcn_mfma_f32_16x16x32_bf16(ka0, va0, acc00, 0, 0, 0);
        acc01 = __builtin_amdgcn_mfma_f32_16x16x32_bf16(ka0, va1, acc01, 0, 0, 0);
        acc10 = __builtin_amdgcn_mfma_f32_16x16x32_bf16(ka1, va0, acc10, 0, 0, 0);
        acc11 = __builtin_amdgcn_mfma_f32_16x16x32_bf16(ka1, va1, acc11, 0, 0, 0);
#pragma unroll
        for (int q2 = 0; q2 < 8; q2++) {
            ksr0 += b2f((ushort)ka0[q2]);
            ksr1 += b2f((ushort)ka1[q2]);
        }
    }
    // ---- block reduction over 4 waves (wave-phased, no atomics) ----
    __syncthreads();
    float* kvred = (float*)kbT;        // 1024 floats <= 10.3KB region
    float* ksumred = (float*)vbT;      // 32 floats
    ksr0 += __shfl_xor(ksr0, 16, 64); ksr0 += __shfl_xor(ksr0, 32, 64);
    ksr1 += __shfl_xor(ksr1, 16, 64); ksr1 += __shfl_xor(ksr1, 32, 64);
    for (int w = 0; w < 4; w++) {
        if (wave == w) {
#pragma unroll
            for (int r = 0; r < 4; r++) {
                int d0i = quad * 4 + r, d1i = 16 + quad * 4 + r;
                int e0 = l16, e1 = 16 + l16;
                if (w == 0) {
                    kvred[d0i * 32 + e0] = acc00[r];
                    kvred[d0i * 32 + e1] = acc01[r];
                    kvred[d1i * 32 + e0] = acc10[r];
                    kvred[d1i * 32 + e1] = acc11[r];
                } else {
                    kvred[d0i * 32 + e0] += acc00[r];
                    kvred[d0i * 32 + e1] += acc01[r];
                    kvred[d1i * 32 + e0] += acc10[r];
                    kvred[d1i * 32 + e1] += acc11[r];
                }
            }
            if (quad == 0) {
                if (w == 0) { ksumred[l16] = ksr0; ksumred[16 + l16] = ksr1; }
                else        { ksumred[l16] += ksr0; ksumred[16 + l16] += ksr1; }
            }
        }
        __syncthreads();
    }
    float4 o4 = *(const float4*)&kvred[t * 4];
    *(float4*)&kv[(bch << 10) + t * 4] = o4;
    if (t < 32) ksum[(bch << 5) + t] = ksumred[t];
}

// ---------------- kv fp32 -> bf16 B-layout, SIDE-MERGED ----------------------
__global__ __launch_bounds__(256) void lft_kvconv_kernel(
    const float* kvbase, ushort* kvtA, ushort* kvtB)
{
    int idx = blockIdx.x;
    int side = idx >> 6, bc = idx & 63;
    const float* kvb = kvbase + (long)side * KVSTRIDE;
    const float* ksb = kvb + 524288;
    ushort* kvt = side ? kvtB : kvtA;
    int t = threadIdx.x;
    int h = t >> 5, d = t & 31;
    const float* kvsrc = kvb + ((long)bc * 8 + h) * 1024;
    const float* kssrc = ksb + ((long)bc * 8 + h) * 32;
    ushort* dst = kvt + ((long)bc * 8 + h) * 1536;
#pragma unroll
    for (int e = 0; e < 32; e++) dst[e * 32 + d] = f2b(kvsrc[d * 32 + e]);
    dst[32 * 32 + d] = f2b(kssrc[d]);
#pragma unroll
    for (int e = 33; e < 48; e++) dst[e * 32 + d] = 0;
}

// ---------------- msg via MFMA, SIDE-MERGED ----------------------------------
__global__ __launch_bounds__(256) void lft_msg_kernel(
    const ushort* qA, const ushort* qB,
    const ushort* kvtA, const ushort* kvtB,
    const int* tlA, const int* tlB, const int* mtA, const int* mtB,
    ushort* msgA_, ushort* msgB_)
{
    int z = blockIdx.z;
    int side = z >> 3, b = z & 7;
    int chunk = blockIdx.x, c = blockIdx.y;
    const ushort* pq = side ? qB : qA;
    const ushort* kvt = side ? kvtB : kvtA;
    const int* tlist = side ? tlB : tlA;
    const int* meta  = side ? mtB : mtA;
    ushort* msg = side ? msgB_ : msgA_;
    int off = meta[(b * 8 + c) * 2], n = meta[(b * 8 + c) * 2 + 1];
    int per = (n + MSG_NCH - 1) / MSG_NCH;
    int s0 = chunk * per, s1 = min(s0 + per, n);
    if (s0 >= s1) return;
    const int* tl = tlist + b * 4800 + off;
    int t = threadIdx.x;
    int wave = t >> 6, lane = t & 63;
    int l16 = lane & 15, quad = lane >> 4;
    int bc = b * 8 + c;
    short8 bfr[2][3];
#pragma unroll
    for (int hh = 0; hh < 2; hh++) {
        int h = wave * 2 + hh;
        const ushort* kb = kvt + ((long)bc * 8 + h) * 1536;
#pragma unroll
        for (int nt = 0; nt < 3; nt++)
            bfr[hh][nt] = *(const short8*)&kb[(nt * 16 + l16) * 32 + quad * 8];
    }
    for (int s = s0; s < s1; s += 16) {
        int ia = min(s + l16, s1 - 1);
        int tokA = tl[ia];
        long rowA = (long)b * 4800 + tokA;
#pragma unroll
        for (int hh = 0; hh < 2; hh++) {
            int h = wave * 2 + hh;
            short8 a = *(const short8*)&pq[rowA * 256 + h * 32 + quad * 8];
            floatx4 n0 = {}, n1 = {}, dd = {};
            n0 = __builtin_amdgcn_mfma_f32_16x16x32_bf16(a, bfr[hh][0], n0, 0, 0, 0);
            n1 = __builtin_amdgcn_mfma_f32_16x16x32_bf16(a, bfr[hh][1], n1, 0, 0, 0);
            dd = __builtin_amdgcn_mfma_f32_16x16x32_bf16(a, bfr[hh][2], dd, 0, 0, 0);
#pragma unroll
            for (int r = 0; r < 4; r++) {
                int rowi = s + quad * 4 + r;
                float den = __shfl(dd[r], lane & 48, 64);
                float inv = 1.f / (den + 1e-6f);
                int tokr = __shfl(tokA, quad * 4 + r, 64);
                if (rowi < s1) {
                    long base = ((long)b * 4800 + tokr) * 256 + h * 32;
                    msg[base + l16]      = f2b(n0[r] * inv);
                    msg[base + 16 + l16] = f2b(n1[r] * inv);
                }
            }
        }
    }
}

extern "C" void kernel_launch(void* const* d_in, const int* in_sizes, int n_in,
                              void* d_out, int out_size, void* d_ws, size_t ws_size,
                              hipStream_t stream)
{
    (void)in_sizes; (void)n_in; (void)out_size; (void)ws_size;
    const float* feat0 = (const float*)d_in[0];
    const float* feat1 = (const float*)d_in[1];
    const int*   mask0 = (const int*)d_in[2];
    const int*   mask1 = (const int*)d_in[3];
    const float* f0wo  = (const float*)d_in[4];
    const float* f1wo  = (const float*)d_in[5];
    const float* proto = (const float*)d_in[6];
    const float* Wq = (const float*)d_in[7];
    const float* Wk = (const float*)d_in[8];
    const float* Wv = (const float*)d_in[9];
    const float* Wm = (const float*)d_in[10];
    const float* W1 = (const float*)d_in[11];
    const float* W2 = (const float*)d_in[12];
    const float* g1 = (const float*)d_in[13];
    const float* b1 = (const float*)d_in[14];
    const float* g2 = (const float*)d_in[15];
    const float* b2 = (const float*)d_in[16];
    float* out = (float*)d_out;
    float* ws = (float*)d_ws;

    // ---- workspace layout ----
    const long FSZ = 9830400L;               // 8*4800*256
    float* fa = ws;
    float* fb = ws + FSZ;
    ushort* kvab0 = (ushort*)(ws + 2 * FSZ);
    ushort* kvab1 = (ushort*)(ws + 3 * FSZ);
    ushort* msgA  = (ushort*)(ws + 2 * FSZ);
    ushort* msgB  = (ushort*)(ws + 2 * FSZ) + FSZ;
    ushort* hidA  = (ushort*)(ws + 3 * FSZ);
    ushort* kvt1  = (ushort*)(ws + 3 * FSZ);
    ushort* ub  = (ushort*)(ws + 4 * FSZ);
    ushort* fa_bf = ub;
    ushort* fb_bf = ub + FSZ;
    ushort* qb1   = ub + 2 * FSZ;
    ushort* qb0   = ub + 3 * FSZ;
    ushort* wb    = ub + 4 * FSZ;
    ushort* wb1   = wb + 16 * 65536;
    ushort* wb2   = wb1 + 4 * 262144;
    ushort* kvt0  = wb2 + 4 * 131072;
    float* kvb = (float*)(kvt0 + 786432);
    int* cls0 = (int*)(kvb + 2 * KVSTRIDE);
    int* cls1 = cls0 + 38400;
    int* tl0  = cls1 + 38400;
    int* tl1  = tl0 + 38400;
    int* meta = tl1 + 38400;

    // one-time per launch
    lft_wconv_kernel<<<dim3(8, 8, 16), 256, 0, stream>>>(Wq, Wk, Wv, Wm, 256, 256, 4, wb);
    lft_wconv_kernel<<<dim3(16, 16, 4), 256, 0, stream>>>(W1, W1, W1, W1, 512, 512, 1, wb1);
    lft_wconv_kernel<<<dim3(16, 8, 4), 256, 0, stream>>>(W2, W2, W2, W2, 512, 256, 1, wb2);
    lft_cast_kernel<<<19200, 256, 0, stream>>>(feat0, feat1, fa_bf, fb_bf);
    hipMemcpyAsync(out + 20352000L, proto, 2048 * 4, hipMemcpyDeviceToDevice, stream);
    lft_class_kernel<<<19200, 256, 0, stream>>>(f0wo, f1wo, mask0, mask1, proto,
                                                out, cls0, cls1);
    lft_sort_kernel<<<16, 256, 0, stream>>>(cls0, cls1, tl0, tl1, meta);

    for (int li = 0; li < 4; li++) {
        const ushort* wq = wb + (size_t)(li * 4 + 0) * 65536;
        const ushort* wk = wb + (size_t)(li * 4 + 1) * 65536;
        const ushort* wm = wb + (size_t)(li * 4 + 3) * 65536;
        const ushort* w1 = wb1 + (size_t)li * 262144;
        const ushort* w2 = wb2 + (size_t)li * 131072;
        const float* g1p = g1 + li * 256; const float* b1p = b1 + li * 256;
        const float* g2p = g2 + li * 256; const float* b2p = b2 + li * 256;
        dim3 blk(256);
        dim3 gA(2, 300), gB(4, 300), gQ(6, 300);

        const float* ra = (li == 0) ? feat0 : fa;
        const float* rb = (li == 0) ? feat1 : fb;
        float* oa = (li == 3) ? out : fa;
        float* ob = (li == 3) ? (out + FSZ) : fb;

        if ((li & 1) == 0) {
            // ===== self-self: merged phase1 (both sides), then phase2 x2 =====
            lft_mfma_gemm<<<gQ, blk, 0, stream>>>(fa_bf, fa_bf, 256, wq,
                nullptr, qb0, 256, 256, 1, 512, kvab0, 512, 256);
            lft_mfma_gemm<<<gQ, blk, 0, stream>>>(fb_bf, fb_bf, 256, wq,
                nullptr, qb1, 256, 256, 1, 512, kvab1, 512, 256);
            lft_kv_kernel<<<dim3(8, 8, 16), blk, 0, stream>>>(
                kvab0, kvab1, tl0, tl1, meta, meta + 128, kvb);
            lft_kvconv_kernel<<<128, blk, 0, stream>>>(kvb, kvt0, kvt1);
            lft_msg_kernel<<<dim3(MSG_NCH, 8, 16), blk, 0, stream>>>(
                qb0, qb1, kvt0, kvt1, tl0, tl1, meta, meta + 128, msgA, msgB);
            lft_gemm_ln<<<600, blk, 0, stream>>>(msgA, wm, 256, g1p, b1p,
                                                 nullptr, nullptr, nullptr, msgA);
            lft_mfma_gemm<<<gB, blk, 0, stream>>>(fa_bf, msgA, 256, w1,
                nullptr, hidA, 512, 512, 2, 512, nullptr, 0, 0);
            lft_gemm_ln<<<600, blk, 0, stream>>>(hidA, w2, 512, g2p, b2p,
                                                 ra, cls0, oa, fa_bf);
            lft_gemm_ln<<<600, blk, 0, stream>>>(msgB, wm, 256, g1p, b1p,
                                                 nullptr, nullptr, nullptr, msgB);
            lft_mfma_gemm<<<gB, blk, 0, stream>>>(fb_bf, msgB, 256, w1,
                nullptr, hidA, 512, 512, 2, 512, nullptr, 0, 0);
            lft_gemm_ln<<<600, blk, 0, stream>>>(hidA, w2, 512, g2p, b2p,
                                                 rb, cls1, ob, fb_bf);
        } else {
            // ===== cross-self: sequential sides =====
            lft_mfma_gemm<<<gA, blk, 0, stream>>>(fa_bf, fa_bf, 256, wq,
                nullptr, qb0, 256, 256, 1, 256, nullptr, 0, 0);
            lft_mfma_gemm<<<gB, blk, 0, stream>>>(fb_bf, fb_bf, 256, wk,
                nullptr, kvab0, 512, 256, 1, 256, nullptr, 0, 0);
            lft_kv_kernel<<<dim3(8, 8, 8), blk, 0, stream>>>(
                kvab0, nullptr, tl1, nullptr, meta + 128, nullptr, kvb);
            lft_kvconv_kernel<<<64, blk, 0, stream>>>(kvb, kvt0, nullptr);
            lft_msg_kernel<<<dim3(MSG_NCH, 8, 8), blk, 0, stream>>>(
                qb0, nullptr, kvt0, nullptr, tl0, nullptr, meta, nullptr, msgA, nullptr);
            lft_gemm_ln<<<600, blk, 0, stream>>>(msgA, wm, 256, g1p, b1p,
                                                 nullptr, nullptr, nullptr, msgA);
            lft_mfma_gemm<<<gB, blk, 0, stream>>>(fa_bf, msgA, 256, w1,
                nullptr, hidA, 512, 512, 2, 512, nullptr, 0, 0);
            lft_gemm_ln<<<600, blk, 0, stream>>>(hidA, w2, 512, g2p, b2p,
                                                 ra, cls0, oa, fa_bf);
            lft_mfma_gemm<<<gA, blk, 0, stream>>>(fb_bf, fb_bf, 256, wq,
                nullptr, qb0, 256, 256, 1, 256, nullptr, 0, 0);
            lft_mfma_gemm<<<gB, blk, 0, stream>>>(fa_bf, fa_bf, 256, wk,
                nullptr, kvab0, 512, 256, 1, 256, nullptr, 0, 0);
            lft_kv_kernel<<<dim3(8, 8, 8), blk, 0, stream>>>(
                kvab0, nullptr, tl0, nullptr, meta, nullptr, kvb);
            lft_kvconv_kernel<<<64, blk, 0, stream>>>(kvb, kvt0, nullptr);
            lft_msg_kernel<<<dim3(MSG_NCH, 8, 8), blk, 0, stream>>>(
                qb0, nullptr, kvt0, nullptr, tl1, nullptr, meta + 128, nullptr, msgA, nullptr);
            lft_gemm_ln<<<600, blk, 0, stream>>>(msgA, wm, 256, g1p, b1p,
                                                 nullptr, nullptr, nullptr, msgA);
            lft_mfma_gemm<<<gB, blk, 0, stream>>>(fb_bf, msgA, 256, w1,
                nullptr, hidA, 512, 512, 2, 512, nullptr, 0, 0);
            lft_gemm_ln<<<600, blk, 0, stream>>>(hidA, w2, 512, g2p, b2p,
                                                 rb, cls1, ob, fb_bf);
        }
    }
}